// Round 10
// baseline (894.885 us; speedup 1.0000x reference)
//
#include <hip/hip_runtime.h>
#include <cstdint>
#include <cstddef>

#define NN 4096
#define EE 131072
#define TS 64

__device__ __forceinline__ unsigned fkey(float f) {
    unsigned u = __float_as_uint(f);
    return (u & 0x80000000u) ? ~u : (u | 0x80000000u);
}
__device__ __forceinline__ float funkey(unsigned k) {
    unsigned u = (k & 0x80000000u) ? (k & 0x7fffffffu) : ~k;
    return __uint_as_float(u);
}

__device__ __forceinline__ float4 max3_4(float4 a, float4 b, float4 c) {
    return make_float4(fmaxf(fmaxf(a.x, b.x), c.x), fmaxf(fmaxf(a.y, b.y), c.y),
                       fmaxf(fmaxf(a.z, b.z), c.z), fmaxf(fmaxf(a.w, b.w), c.w));
}
__device__ __forceinline__ unsigned bit_sext(unsigned w, unsigned off) {
#if __has_builtin(__builtin_amdgcn_sbfe)
    return (unsigned)__builtin_amdgcn_sbfe((int)w, off, 1u);
#else
    return (unsigned)(-(int)((w >> off) & 1u));
#endif
}
__device__ __forceinline__ unsigned bit_sext_s(unsigned w, int off) {
    return (unsigned)(((int)(w << (31 - off))) >> 31);
}
__device__ __forceinline__ float4 and4(unsigned m, float4 v) {
    return make_float4(__uint_as_float(m & __float_as_uint(v.x)),
                       __uint_as_float(m & __float_as_uint(v.y)),
                       __uint_as_float(m & __float_as_uint(v.z)),
                       __uint_as_float(m & __float_as_uint(v.w)));
}
// atomic max for non-negative floats (bits order as unsigned ints)
__device__ __forceinline__ void amax4(float* p, float4 v) {
    atomicMax((int*)p + 0, __float_as_int(v.x));
    atomicMax((int*)p + 1, __float_as_int(v.y));
    atomicMax((int*)p + 2, __float_as_int(v.z));
    atomicMax((int*)p + 3, __float_as_int(v.w));
}

__global__ void k_count(const int* __restrict__ src, const int* __restrict__ dst,
                        int* __restrict__ cs, int* __restrict__ cd) {
    int e = blockIdx.x * 256 + threadIdx.x;
    if (e < EE) {
        atomicAdd(&cs[src[e]], 1);
        atomicAdd(&cd[dst[e]], 1);
    }
}

__global__ void k_norm(const int* __restrict__ cs, const int* __restrict__ cd,
                       float* __restrict__ on, float* __restrict__ inn) {
    int i = blockIdx.x * 256 + threadIdx.x;
    if (i < NN) {
        int a = cs[i] > 1 ? cs[i] : 1;
        int b = cd[i] > 1 ? cd[i] : 1;
        on[i]  = 1.0f / sqrtf((float)a);
        inn[i] = 1.0f / sqrtf((float)b);
    }
}

template<int K, int ND>
__global__ void k_gemm_scale(const float* __restrict__ X, const float* __restrict__ W,
                             const float* __restrict__ scale, float* __restrict__ out) {
    __shared__ float xr[K];
    int i = blockIdx.x;
    for (int k = threadIdx.x; k < K; k += ND) xr[k] = X[(size_t)i * K + k];
    __syncthreads();
    int j = threadIdx.x;
    float acc = 0.0f;
    #pragma unroll 8
    for (int k = 0; k < K; ++k) acc = fmaf(xr[k], W[k * ND + j], acc);
    out[(size_t)i * ND + j] = acc * scale[i];
}

// out[i][j] = X@W + b1[j] (+ b2[j]) (optional relu).
template<int K, int ND>
__global__ void k_gemm_ab(const float* __restrict__ X, const float* __restrict__ W,
                          const float* __restrict__ b1, const float* __restrict__ b2,
                          float* __restrict__ out, int do_relu) {
    __shared__ float xr[K];
    int i = blockIdx.x;
    for (int k = threadIdx.x; k < K; k += ND) xr[k] = X[(size_t)i * K + k];
    __syncthreads();
    int j = threadIdx.x;
    float acc = 0.0f;
    #pragma unroll 8
    for (int k = 0; k < K; ++k) acc = fmaf(xr[k], W[k * ND + j], acc);
    acc += b1[j];
    if (b2) acc += b2[j];
    if (do_relu) acc = fmaxf(acc, 0.0f);
    out[(size_t)i * ND + j] = acc;
}

__global__ void k_scatter(const float* __restrict__ t, const int* __restrict__ src,
                          const int* __restrict__ dst, float* __restrict__ agg) {
    int e = blockIdx.x;
    int j = threadIdx.x;   // 128 threads
    int s = src[e], d = dst[e];
    atomicAdd(&agg[(size_t)d * 128 + j], t[(size_t)s * 128 + j]);
}

__global__ void k_gcn_out(const float* __restrict__ agg, const float* __restrict__ inn,
                          const float* __restrict__ b, float* __restrict__ out, int do_relu) {
    int idx = blockIdx.x * 256 + threadIdx.x;
    int i = idx >> 7, j = idx & 127;
    float v = agg[idx] * inn[i] + b[j];
    if (do_relu) v = fmaxf(v, 0.0f);
    out[idx] = v;
}

// ---- S = h h^T 64x64 tile; MODE 0: max-only; MODE 1: recompute + bit-emit ----
template<int MODE>
__global__ __launch_bounds__(256, 4) void k_stile(const float* __restrict__ h,
                                                  const float* __restrict__ u,
                                                  unsigned* __restrict__ smax_key,
                                                  unsigned* __restrict__ mb) {
    int ti = blockIdx.y, tj = blockIdx.x;
    if (tj < ti) return;
    __shared__ float Ah[TS][68];
    __shared__ float Bh[TS][68];
    int tid = threadIdx.x;
    int tx = tid & 15, ty = tid >> 4;
    const float* ha = h + (size_t)ti * TS * 128;
    const float* hb = h + (size_t)tj * TS * 128;

    float acc[4][4];
    #pragma unroll
    for (int r = 0; r < 4; ++r)
        #pragma unroll
        for (int c = 0; c < 4; ++c) acc[r][c] = 0.0f;

    for (int half = 0; half < 2; ++half) {
        __syncthreads();
        #pragma unroll
        for (int t = 0; t < 4; ++t) {
            int f = tid + t * 256;
            int row = f >> 4, kk = f & 15;
            *(float4*)&Ah[row][kk * 4] = *(const float4*)(ha + (size_t)row * 128 + half * 64 + kk * 4);
            *(float4*)&Bh[row][kk * 4] = *(const float4*)(hb + (size_t)row * 128 + half * 64 + kk * 4);
        }
        __syncthreads();
        #pragma unroll 2
        for (int k4 = 0; k4 < 16; ++k4) {
            float4 a[4], b[4];
            #pragma unroll
            for (int r = 0; r < 4; ++r) a[r] = *(const float4*)&Ah[ty + 16 * r][k4 * 4];
            #pragma unroll
            for (int c = 0; c < 4; ++c) b[c] = *(const float4*)&Bh[tx + 16 * c][k4 * 4];
            #pragma unroll
            for (int r = 0; r < 4; ++r)
                #pragma unroll
                for (int c = 0; c < 4; ++c) {
                    acc[r][c] = fmaf(a[r].x, b[c].x, acc[r][c]);
                    acc[r][c] = fmaf(a[r].y, b[c].y, acc[r][c]);
                    acc[r][c] = fmaf(a[r].z, b[c].z, acc[r][c]);
                    acc[r][c] = fmaf(a[r].w, b[c].w, acc[r][c]);
                }
        }
    }

    if constexpr (MODE == 0) {
        float m = -3.4e38f;
        #pragma unroll
        for (int r = 0; r < 4; ++r)
            #pragma unroll
            for (int c = 0; c < 4; ++c) m = fmaxf(m, acc[r][c]);
        #pragma unroll
        for (int o = 1; o < 64; o <<= 1) m = fmaxf(m, __shfl_xor(m, o, 64));
        __shared__ float wm[4];
        if ((tid & 63) == 0) wm[tid >> 6] = m;
        __syncthreads();
        if (tid == 0) {
            float mm = fmaxf(fmaxf(wm[0], wm[1]), fmaxf(wm[2], wm[3]));
            atomicMax(smax_key, fkey(mm));
        }
    } else {
        float smax = funkey(*smax_key);
        float epmax = 1.0f / (1.0f + expf(-smax));
        __shared__ unsigned lm[TS][2];
        __shared__ unsigned lmT[TS][2];
        if (tid < 128) { lm[tid >> 1][tid & 1] = 0u; lmT[tid >> 1][tid & 1] = 0u; }
        __syncthreads();
        #pragma unroll
        for (int r = 0; r < 4; ++r) {
            #pragma unroll
            for (int c = 0; c < 4; ++c) {
                int li = ty + 16 * r, lj = tx + 16 * c;
                int gi = ti * TS + li, gj = tj * TS + lj;
                bool bit = false;
                if (gi < gj) {
                    float ep = 1.0f / (1.0f + expf(-acc[r][c]));
                    float P = ep / epmax;
                    float Pc = fminf(fmaxf(P, 1e-6f), 1.0f - 1e-6f);
                    float uu = u[(size_t)gi * NN + gj];
                    float ucv = fminf(fmaxf(uu, 1e-6f), 1.0f - 1e-6f);
                    bit = Pc > (1.0f - ucv);
                } else if (gi == gj) {
                    bit = true;
                }
                if (bit) {
                    atomicOr(&lm[li][lj >> 5], 1u << (lj & 31));
                    atomicOr(&lmT[lj][li >> 5], 1u << (li & 31));
                }
            }
        }
        __syncthreads();
        if (tid < 128) {
            int r = tid >> 1, wq = tid & 1;
            unsigned word = lm[r][wq];
            if (ti == tj) word |= lmT[r][wq];
            mb[(size_t)(ti * TS + r) * 128 + tj * 2 + wq] = word;
        } else if (ti != tj) {
            int r = (tid - 128) >> 1, wq = tid & 1;
            mb[(size_t)(tj * TS + r) * 128 + ti * 2 + wq] = lmT[r][wq];
        }
    }
}

// Pass 1 (S-store path): compute tile, store S to ws, fold into global max.
__global__ __launch_bounds__(256, 4) void k_stile_store(const float* __restrict__ h,
                                                        float* __restrict__ S,
                                                        unsigned* __restrict__ smax_key) {
    int ti = blockIdx.y, tj = blockIdx.x;
    if (tj < ti) return;
    __shared__ float Ah[TS][68];
    __shared__ float Bh[TS][68];
    int tid = threadIdx.x;
    int tx = tid & 15, ty = tid >> 4;
    const float* ha = h + (size_t)ti * TS * 128;
    const float* hb = h + (size_t)tj * TS * 128;

    float acc[4][4];
    #pragma unroll
    for (int r = 0; r < 4; ++r)
        #pragma unroll
        for (int c = 0; c < 4; ++c) acc[r][c] = 0.0f;

    for (int half = 0; half < 2; ++half) {
        __syncthreads();
        #pragma unroll
        for (int t = 0; t < 4; ++t) {
            int f = tid + t * 256;
            int row = f >> 4, kk = f & 15;
            *(float4*)&Ah[row][kk * 4] = *(const float4*)(ha + (size_t)row * 128 + half * 64 + kk * 4);
            *(float4*)&Bh[row][kk * 4] = *(const float4*)(hb + (size_t)row * 128 + half * 64 + kk * 4);
        }
        __syncthreads();
        #pragma unroll 2
        for (int k4 = 0; k4 < 16; ++k4) {
            float4 a[4], b[4];
            #pragma unroll
            for (int r = 0; r < 4; ++r) a[r] = *(const float4*)&Ah[ty + 16 * r][k4 * 4];
            #pragma unroll
            for (int c = 0; c < 4; ++c) b[c] = *(const float4*)&Bh[tx + 16 * c][k4 * 4];
            #pragma unroll
            for (int r = 0; r < 4; ++r)
                #pragma unroll
                for (int c = 0; c < 4; ++c) {
                    acc[r][c] = fmaf(a[r].x, b[c].x, acc[r][c]);
                    acc[r][c] = fmaf(a[r].y, b[c].y, acc[r][c]);
                    acc[r][c] = fmaf(a[r].z, b[c].z, acc[r][c]);
                    acc[r][c] = fmaf(a[r].w, b[c].w, acc[r][c]);
                }
        }
    }

    float* sp = S + (size_t)(ti * 64 + tj) * 4096;
    #pragma unroll
    for (int r = 0; r < 4; ++r)
        #pragma unroll
        for (int c = 0; c < 4; ++c)
            sp[(ty + 16 * r) * 64 + tx + 16 * c] = acc[r][c];

    float m = -3.4e38f;
    #pragma unroll
    for (int r = 0; r < 4; ++r)
        #pragma unroll
        for (int c = 0; c < 4; ++c) m = fmaxf(m, acc[r][c]);
    #pragma unroll
    for (int o = 1; o < 64; o <<= 1) m = fmaxf(m, __shfl_xor(m, o, 64));
    __shared__ float wm[4];
    if ((tid & 63) == 0) wm[tid >> 6] = m;
    __syncthreads();
    if (tid == 0)
        atomicMax(smax_key, fkey(fmaxf(fmaxf(wm[0], wm[1]), fmaxf(wm[2], wm[3]))));
}

// Pass 2 (S-store path): read stored S, emit mask bits.
__global__ __launch_bounds__(256, 4) void k_bitemit(const float* __restrict__ S,
                                                    const float* __restrict__ u,
                                                    const unsigned* __restrict__ smax_key,
                                                    unsigned* __restrict__ mb) {
    int ti = blockIdx.y, tj = blockIdx.x;
    if (tj < ti) return;
    int tid = threadIdx.x;
    int tx = tid & 15, ty = tid >> 4;
    float smax = funkey(*smax_key);
    float epmax = 1.0f / (1.0f + expf(-smax));
    __shared__ unsigned lm[TS][2];
    __shared__ unsigned lmT[TS][2];
    if (tid < 128) { lm[tid >> 1][tid & 1] = 0u; lmT[tid >> 1][tid & 1] = 0u; }
    __syncthreads();
    const float* sp = S + (size_t)(ti * 64 + tj) * 4096;
    #pragma unroll
    for (int r = 0; r < 4; ++r) {
        #pragma unroll
        for (int c = 0; c < 4; ++c) {
            int li = ty + 16 * r, lj = tx + 16 * c;
            int gi = ti * TS + li, gj = tj * TS + lj;
            bool bit = false;
            if (gi < gj) {
                float ep = 1.0f / (1.0f + expf(-sp[li * 64 + lj]));
                float P = ep / epmax;
                float Pc = fminf(fmaxf(P, 1e-6f), 1.0f - 1e-6f);
                float uu = u[(size_t)gi * NN + gj];
                float ucv = fminf(fmaxf(uu, 1e-6f), 1.0f - 1e-6f);
                bit = Pc > (1.0f - ucv);
            } else if (gi == gj) {
                bit = true;
            }
            if (bit) {
                atomicOr(&lm[li][lj >> 5], 1u << (lj & 31));
                atomicOr(&lmT[lj][li >> 5], 1u << (li & 31));
            }
        }
    }
    __syncthreads();
    if (tid < 128) {
        int r = tid >> 1, wq = tid & 1;
        unsigned word = lm[r][wq];
        if (ti == tj) word |= lmT[r][wq];
        mb[(size_t)(ti * TS + r) * 128 + tj * 2 + wq] = word;
    } else if (ti != tj) {
        int r = (tid - 128) >> 1, wq = tid & 1;
        mb[(size_t)(tj * TS + r) * 128 + ti * 2 + wq] = lmT[r][wq];
    }
}

// Masked max, D=256, partials merged via global atomicMax (valid: z >= 0).
// RT=32 rows/block (8/thread), JS=16 segments -> 2048 blocks = 8/CU = full
// occupancy; wave-uniform mask via readfirstlane + scalar sext, and4+max3.
template<int RT, int JS>
__global__ __launch_bounds__(256, 8) void k_mmax256(const unsigned* __restrict__ mb,
                                                    const float* __restrict__ z,
                                                    float* __restrict__ pm) {
    constexpr int JPS = NN / JS;   // 256
    constexpr int WPS = JPS / 32;  // 8
    constexpr int RPG = RT / 4;    // 8
    constexpr int NRB = NN / RT;   // 128
    int rowblk = blockIdx.x % NRB, js = blockIdx.x / NRB;
    int i0 = rowblk * RT;

    __shared__ unsigned msk[RT][WPS + 1];
    {
        int t = threadIdx.x;           // RT*WPS == 256
        msk[t / WPS][t % WPS] = mb[(size_t)(i0 + t / WPS) * 128 + js * WPS + t % WPS];
    }
    __syncthreads();

    int d4 = threadIdx.x & 63;
    int g = threadIdx.x >> 6;
    const float4* zbase = (const float4*)z + (size_t)js * JPS * 64 + d4;

    float4 acc[RPG];
    #pragma unroll
    for (int r = 0; r < RPG; ++r) acc[r] = make_float4(0.f, 0.f, 0.f, 0.f);

    #pragma unroll 1
    for (int wq = 0; wq < WPS; ++wq) {
        unsigned m[RPG];
        #pragma unroll
        for (int r = 0; r < RPG; ++r)
            m[r] = (unsigned)__builtin_amdgcn_readfirstlane((int)msk[g * RPG + r][wq]);
        const float4* zp = zbase + (size_t)(wq * 32) * 64;
        #pragma unroll 2
        for (int j4 = 0; j4 < 32; j4 += 4) {
            float4 z0 = zp[0 * 64];
            float4 z1 = zp[1 * 64];
            float4 z2 = zp[2 * 64];
            float4 z3 = zp[3 * 64];
            #pragma unroll
            for (int r = 0; r < RPG; ++r) {
                unsigned s0 = bit_sext_s(m[r], j4 + 0);
                unsigned s1 = bit_sext_s(m[r], j4 + 1);
                unsigned s2 = bit_sext_s(m[r], j4 + 2);
                unsigned s3 = bit_sext_s(m[r], j4 + 3);
                acc[r] = max3_4(acc[r], and4(s0, z0), and4(s1, z1));
                acc[r] = max3_4(acc[r], and4(s2, z2), and4(s3, z3));
            }
            zp += 4 * 64;
        }
    }

    #pragma unroll
    for (int r = 0; r < RPG; ++r)
        amax4(pm + (size_t)(i0 + g * RPG + r) * 256 + d4 * 4, acc[r]);
}

// Masked max, D=128, atomic-merged. Wave covers 2 j's (jpar = lane>>5).
template<int RT, int JS>
__global__ __launch_bounds__(256, 8) void k_mmax128(const unsigned* __restrict__ mb,
                                                    const float* __restrict__ z,
                                                    float* __restrict__ pm) {
    constexpr int JPS = NN / JS;   // 256
    constexpr int WPS = JPS / 32;  // 8
    constexpr int RPG = RT / 4;    // 8
    constexpr int NRB = NN / RT;   // 128
    int rowblk = blockIdx.x % NRB, js = blockIdx.x / NRB;
    int i0 = rowblk * RT;

    __shared__ unsigned msk[RT][WPS + 1];
    {
        int t = threadIdx.x;
        msk[t / WPS][t % WPS] = mb[(size_t)(i0 + t / WPS) * 128 + js * WPS + t % WPS];
    }
    __syncthreads();

    int lane = threadIdx.x & 63;
    int g = threadIdx.x >> 6;
    unsigned jpar = lane >> 5;
    int d4 = lane & 31;
    const float4* zbase = (const float4*)z + (size_t)js * JPS * 32 + d4;

    float4 acc[RPG];
    #pragma unroll
    for (int r = 0; r < RPG; ++r) acc[r] = make_float4(0.f, 0.f, 0.f, 0.f);

    #pragma unroll 1
    for (int wq = 0; wq < WPS; ++wq) {
        unsigned m[RPG];
        #pragma unroll
        for (int r = 0; r < RPG; ++r) m[r] = msk[g * RPG + r][wq];
        const float4* zp = zbase + (size_t)(wq * 32) * 32;
        #pragma unroll 2
        for (int j4 = 0; j4 < 32; j4 += 4) {
            float4 za = zp[(size_t)jpar * 32];
            float4 zb = zp[(size_t)(2 + jpar) * 32];
            unsigned oa = j4 + jpar, ob = j4 + 2 + jpar;
            #pragma unroll
            for (int r = 0; r < RPG; ++r) {
                unsigned sa = bit_sext(m[r], oa);
                unsigned sb = bit_sext(m[r], ob);
                acc[r] = max3_4(acc[r], and4(sa, za), and4(sb, zb));
            }
            zp += 4 * 32;
        }
    }

    #pragma unroll
    for (int r = 0; r < RPG; ++r) {
        acc[r].x = fmaxf(acc[r].x, __shfl_xor(acc[r].x, 32, 64));
        acc[r].y = fmaxf(acc[r].y, __shfl_xor(acc[r].y, 32, 64));
        acc[r].z = fmaxf(acc[r].z, __shfl_xor(acc[r].z, 32, 64));
        acc[r].w = fmaxf(acc[r].w, __shfl_xor(acc[r].w, 32, 64));
    }
    if (!jpar) {
        #pragma unroll
        for (int r = 0; r < RPG; ++r)
            amax4(pm + (size_t)(i0 + g * RPG + r) * 128 + d4 * 4, acc[r]);
    }
}

__global__ void k_relu_l2norm(float* __restrict__ h) {
    int i = blockIdx.x, d = threadIdx.x;
    float v = fmaxf(h[(size_t)i * 128 + d], 0.0f);
    float ss = v * v;
    #pragma unroll
    for (int o = 1; o < 64; o <<= 1) ss += __shfl_xor(ss, o, 64);
    __shared__ float w2[2];
    if ((d & 63) == 0) w2[d >> 6] = ss;
    __syncthreads();
    float tot = w2[0] + w2[1];
    float denom = fmaxf(sqrtf(tot), 1e-12f);
    h[(size_t)i * 128 + d] = v / denom;
}

// Final 128->32 GEMM, LDS-staged, 4 rows per block.
__global__ void k_gemm_final(const float* __restrict__ X, const float* __restrict__ W,
                             const float* __restrict__ b1, const float* __restrict__ b2,
                             float* __restrict__ out) {
    __shared__ float xr[4][128];
    int i0 = blockIdx.x * 4;
    for (int t = threadIdx.x; t < 512; t += 128) {
        int r = t >> 7, k = t & 127;
        xr[r][k] = X[(size_t)(i0 + r) * 128 + k];
    }
    __syncthreads();
    int il = threadIdx.x >> 5, j = threadIdx.x & 31;
    float acc = 0.0f;
    #pragma unroll 8
    for (int k = 0; k < 128; ++k) acc = fmaf(xr[il][k], W[k * 32 + j], acc);
    out[(size_t)(i0 + il) * 32 + j] = acc + b1[j] + b2[j];
}

extern "C" void kernel_launch(void* const* d_in, const int* in_sizes, int n_in,
                              void* d_out, int out_size, void* d_ws, size_t ws_size,
                              hipStream_t stream) {
    const float* inputs = (const float*)d_in[1];
    const float* feat   = (const float*)d_in[2];
    const float* u      = (const float*)d_in[3];
    const int*   src    = (const int*)d_in[4];
    const int*   dst    = (const int*)d_in[5];
    const float* gc0W = (const float*)d_in[6],  *gc0b = (const float*)d_in[7];
    const float* gc1W = (const float*)d_in[8],  *gc1b = (const float*)d_in[9];
    const float* p0W  = (const float*)d_in[10], *p0b  = (const float*)d_in[11];
    const float* l0W  = (const float*)d_in[12], *l0b  = (const float*)d_in[13];
    const float* b0   = (const float*)d_in[14];
    const float* p1W  = (const float*)d_in[15], *p1b  = (const float*)d_in[16];
    const float* l1W  = (const float*)d_in[17], *l1b  = (const float*)d_in[18];
    const float* b1   = (const float*)d_in[19];
    const float* p2W  = (const float*)d_in[20], *p2b  = (const float*)d_in[21];
    const float* l2W  = (const float*)d_in[22], *l2b  = (const float*)d_in[23];
    const float* b2   = (const float*)d_in[24];
    float* out = (float*)d_out;

    const size_t MB = 1048576;
    char* w = (char*)d_ws;
    int*      cnt_src  = (int*)(w + 0);            // 16 KB
    int*      cnt_dst  = (int*)(w + 16384);        // 16 KB
    float*    on       = (float*)(w + 32768);      // 16 KB
    float*    inn      = (float*)(w + 49152);      // 16 KB
    unsigned* smax_key = (unsigned*)(w + 65536);   // pad to 128 KB
    char*     big      = w + 131072;
    float*    tmp      = (float*)(big);            // 2 MB
    float*    agg      = (float*)(big + 2 * MB);   // 2 MB
    float*    hbuf     = (float*)(big + 4 * MB);   // 2 MB
    unsigned* mb       = (unsigned*)(big + 6 * MB);// 2 MB
    float*    z        = (float*)(big + 8 * MB);   // 4 MB
    float*    pm       = (float*)(big + 12 * MB);  // 4 MB (atomic-merged)
    float*    hs       = (float*)(big + 16 * MB);  // 2 MB
    float*    Sbuf     = (float*)(big + 18 * MB);  // 64 MB
    bool use_sstore = ws_size >= 131072 + 82 * MB;

    hipMemsetAsync(w, 0, 131072, stream);
    k_count<<<EE / 256, 256, 0, stream>>>(src, dst, cnt_src, cnt_dst);
    k_norm<<<NN / 256, 256, 0, stream>>>(cnt_src, cnt_dst, on, inn);

    // --- GCN layer 0 ---
    k_gemm_scale<256, 128><<<NN, 128, 0, stream>>>(inputs, gc0W, on, tmp);
    hipMemsetAsync(agg, 0, (size_t)NN * 128 * 4, stream);
    k_scatter<<<EE, 128, 0, stream>>>(tmp, src, dst, agg);
    k_gcn_out<<<NN * 128 / 256, 256, 0, stream>>>(agg, inn, gc0b, hbuf, 1);

    // --- GCN layer 1 ---
    k_gemm_scale<128, 128><<<NN, 128, 0, stream>>>(hbuf, gc1W, on, tmp);
    hipMemsetAsync(agg, 0, (size_t)NN * 128 * 4, stream);
    k_scatter<<<EE, 128, 0, stream>>>(tmp, src, dst, agg);
    k_gcn_out<<<NN * 128 / 256, 256, 0, stream>>>(agg, inn, gc1b, hbuf, 0);

    // --- decode: S max + mask bits ---
    dim3 tg(64, 64);
    if (use_sstore) {
        k_stile_store<<<tg, 256, 0, stream>>>(hbuf, Sbuf, smax_key);
        k_bitemit<<<tg, 256, 0, stream>>>(Sbuf, u, smax_key, mb);
    } else {
        k_stile<0><<<tg, 256, 0, stream>>>(hbuf, nullptr, smax_key, nullptr);
        k_stile<1><<<tg, 256, 0, stream>>>(hbuf, u, smax_key, mb);
    }

    // --- GraphSAGE layer 0 (256 -> 128) ---
    k_gemm_ab<256, 256><<<NN, 256, 0, stream>>>(feat, p0W, p0b, nullptr, z, 1);
    hipMemsetAsync(pm, 0, (size_t)NN * 256 * 4, stream);
    k_mmax256<32, 16><<<(NN / 32) * 16, 256, 0, stream>>>(mb, z, pm);
    k_gemm_ab<256, 128><<<NN, 128, 0, stream>>>(pm, l0W, l0b, b0, hs, 0);
    k_relu_l2norm<<<NN, 128, 0, stream>>>(hs);

    // --- GraphSAGE layer 1 (128 -> 128) ---
    k_gemm_ab<128, 128><<<NN, 128, 0, stream>>>(hs, p1W, p1b, nullptr, z, 1);
    hipMemsetAsync(pm, 0, (size_t)NN * 128 * 4, stream);
    k_mmax128<32, 16><<<(NN / 32) * 16, 256, 0, stream>>>(mb, z, pm);
    k_gemm_ab<128, 128><<<NN, 128, 0, stream>>>(pm, l1W, l1b, b1, tmp, 0);
    k_relu_l2norm<<<NN, 128, 0, stream>>>(tmp);

    // --- GraphSAGE layer 2 (128 -> 32) ---
    k_gemm_ab<128, 128><<<NN, 128, 0, stream>>>(tmp, p2W, p2b, nullptr, z, 1);
    hipMemsetAsync(pm, 0, (size_t)NN * 128 * 4, stream);
    k_mmax128<32, 16><<<(NN / 32) * 16, 256, 0, stream>>>(mb, z, pm);
    k_gemm_final<<<NN / 4, 128, 0, stream>>>(pm, l2W, l2b, b2, out);
}

// Round 11
// 767.758 us; speedup vs baseline: 1.1656x; 1.1656x over previous
//
#include <hip/hip_runtime.h>
#include <cstdint>
#include <cstddef>

#define NN 4096
#define EE 131072
#define TS 64

__device__ __forceinline__ unsigned fkey(float f) {
    unsigned u = __float_as_uint(f);
    return (u & 0x80000000u) ? ~u : (u | 0x80000000u);
}
__device__ __forceinline__ float funkey(unsigned k) {
    unsigned u = (k & 0x80000000u) ? (k & 0x7fffffffu) : ~k;
    return __uint_as_float(u);
}

__device__ __forceinline__ float4 max3_4(float4 a, float4 b, float4 c) {
    return make_float4(fmaxf(fmaxf(a.x, b.x), c.x), fmaxf(fmaxf(a.y, b.y), c.y),
                       fmaxf(fmaxf(a.z, b.z), c.z), fmaxf(fmaxf(a.w, b.w), c.w));
}
__device__ __forceinline__ unsigned bit_sext(unsigned w, unsigned off) {
#if __has_builtin(__builtin_amdgcn_sbfe)
    return (unsigned)__builtin_amdgcn_sbfe((int)w, off, 1u);
#else
    return (unsigned)(-(int)((w >> off) & 1u));
#endif
}
__device__ __forceinline__ unsigned bit_sext_s(unsigned w, int off) {
    return (unsigned)(((int)(w << (31 - off))) >> 31);
}
__device__ __forceinline__ float4 and4(unsigned m, float4 v) {
    return make_float4(__uint_as_float(m & __float_as_uint(v.x)),
                       __uint_as_float(m & __float_as_uint(v.y)),
                       __uint_as_float(m & __float_as_uint(v.z)),
                       __uint_as_float(m & __float_as_uint(v.w)));
}

__global__ void k_count(const int* __restrict__ src, const int* __restrict__ dst,
                        int* __restrict__ cs, int* __restrict__ cd) {
    int e = blockIdx.x * 256 + threadIdx.x;
    if (e < EE) {
        atomicAdd(&cs[src[e]], 1);
        atomicAdd(&cd[dst[e]], 1);
    }
}

__global__ void k_norm(const int* __restrict__ cs, const int* __restrict__ cd,
                       float* __restrict__ on, float* __restrict__ inn) {
    int i = blockIdx.x * 256 + threadIdx.x;
    if (i < NN) {
        int a = cs[i] > 1 ? cs[i] : 1;
        int b = cd[i] > 1 ? cd[i] : 1;
        on[i]  = 1.0f / sqrtf((float)a);
        inn[i] = 1.0f / sqrtf((float)b);
    }
}

template<int K, int ND>
__global__ void k_gemm_scale(const float* __restrict__ X, const float* __restrict__ W,
                             const float* __restrict__ scale, float* __restrict__ out) {
    __shared__ float xr[K];
    int i = blockIdx.x;
    for (int k = threadIdx.x; k < K; k += ND) xr[k] = X[(size_t)i * K + k];
    __syncthreads();
    int j = threadIdx.x;
    float acc = 0.0f;
    #pragma unroll 8
    for (int k = 0; k < K; ++k) acc = fmaf(xr[k], W[k * ND + j], acc);
    out[(size_t)i * ND + j] = acc * scale[i];
}

// out[i][j] = (max over NS split-partials of X)[i][:] @ W + b1 (+b2) (opt relu).
template<int K, int ND, int NS>
__global__ void k_gemm_mrg(const float* __restrict__ X, size_t xstride,
                           const float* __restrict__ W,
                           const float* __restrict__ b1, const float* __restrict__ b2,
                           float* __restrict__ out, int do_relu) {
    __shared__ float xr[K];
    int i = blockIdx.x;
    for (int k = threadIdx.x; k < K; k += ND) {
        float v = X[(size_t)i * K + k];
        #pragma unroll
        for (int s = 1; s < NS; ++s)
            v = fmaxf(v, X[(size_t)s * xstride + (size_t)i * K + k]);
        xr[k] = v;
    }
    __syncthreads();
    int j = threadIdx.x;
    float acc = 0.0f;
    #pragma unroll 8
    for (int k = 0; k < K; ++k) acc = fmaf(xr[k], W[k * ND + j], acc);
    acc += b1[j];
    if (b2) acc += b2[j];
    if (do_relu) acc = fmaxf(acc, 0.0f);
    out[(size_t)i * ND + j] = acc;
}

__global__ void k_scatter(const float* __restrict__ t, const int* __restrict__ src,
                          const int* __restrict__ dst, float* __restrict__ agg) {
    int e = blockIdx.x;
    int j = threadIdx.x;   // 128 threads
    int s = src[e], d = dst[e];
    atomicAdd(&agg[(size_t)d * 128 + j], t[(size_t)s * 128 + j]);
}

__global__ void k_gcn_out(const float* __restrict__ agg, const float* __restrict__ inn,
                          const float* __restrict__ b, float* __restrict__ out, int do_relu) {
    int idx = blockIdx.x * 256 + threadIdx.x;
    int i = idx >> 7, j = idx & 127;
    float v = agg[idx] * inn[i] + b[j];
    if (do_relu) v = fmaxf(v, 0.0f);
    out[idx] = v;
}

// ---- S = h h^T 64x64 tile; MODE 0: max-only; MODE 1: recompute + bit-emit ----
template<int MODE>
__global__ __launch_bounds__(256, 4) void k_stile(const float* __restrict__ h,
                                                  const float* __restrict__ u,
                                                  unsigned* __restrict__ smax_key,
                                                  unsigned* __restrict__ mb) {
    int ti = blockIdx.y, tj = blockIdx.x;
    if (tj < ti) return;
    __shared__ float Ah[TS][68];
    __shared__ float Bh[TS][68];
    int tid = threadIdx.x;
    int tx = tid & 15, ty = tid >> 4;
    const float* ha = h + (size_t)ti * TS * 128;
    const float* hb = h + (size_t)tj * TS * 128;

    float acc[4][4];
    #pragma unroll
    for (int r = 0; r < 4; ++r)
        #pragma unroll
        for (int c = 0; c < 4; ++c) acc[r][c] = 0.0f;

    for (int half = 0; half < 2; ++half) {
        __syncthreads();
        #pragma unroll
        for (int t = 0; t < 4; ++t) {
            int f = tid + t * 256;
            int row = f >> 4, kk = f & 15;
            *(float4*)&Ah[row][kk * 4] = *(const float4*)(ha + (size_t)row * 128 + half * 64 + kk * 4);
            *(float4*)&Bh[row][kk * 4] = *(const float4*)(hb + (size_t)row * 128 + half * 64 + kk * 4);
        }
        __syncthreads();
        #pragma unroll 2
        for (int k4 = 0; k4 < 16; ++k4) {
            float4 a[4], b[4];
            #pragma unroll
            for (int r = 0; r < 4; ++r) a[r] = *(const float4*)&Ah[ty + 16 * r][k4 * 4];
            #pragma unroll
            for (int c = 0; c < 4; ++c) b[c] = *(const float4*)&Bh[tx + 16 * c][k4 * 4];
            #pragma unroll
            for (int r = 0; r < 4; ++r)
                #pragma unroll
                for (int c = 0; c < 4; ++c) {
                    acc[r][c] = fmaf(a[r].x, b[c].x, acc[r][c]);
                    acc[r][c] = fmaf(a[r].y, b[c].y, acc[r][c]);
                    acc[r][c] = fmaf(a[r].z, b[c].z, acc[r][c]);
                    acc[r][c] = fmaf(a[r].w, b[c].w, acc[r][c]);
                }
        }
    }

    if constexpr (MODE == 0) {
        float m = -3.4e38f;
        #pragma unroll
        for (int r = 0; r < 4; ++r)
            #pragma unroll
            for (int c = 0; c < 4; ++c) m = fmaxf(m, acc[r][c]);
        #pragma unroll
        for (int o = 1; o < 64; o <<= 1) m = fmaxf(m, __shfl_xor(m, o, 64));
        __shared__ float wm[4];
        if ((tid & 63) == 0) wm[tid >> 6] = m;
        __syncthreads();
        if (tid == 0) {
            float mm = fmaxf(fmaxf(wm[0], wm[1]), fmaxf(wm[2], wm[3]));
            atomicMax(smax_key, fkey(mm));
        }
    } else {
        float smax = funkey(*smax_key);
        float epmax = 1.0f / (1.0f + expf(-smax));
        __shared__ unsigned lm[TS][2];
        __shared__ unsigned lmT[TS][2];
        if (tid < 128) { lm[tid >> 1][tid & 1] = 0u; lmT[tid >> 1][tid & 1] = 0u; }
        __syncthreads();
        #pragma unroll
        for (int r = 0; r < 4; ++r) {
            #pragma unroll
            for (int c = 0; c < 4; ++c) {
                int li = ty + 16 * r, lj = tx + 16 * c;
                int gi = ti * TS + li, gj = tj * TS + lj;
                bool bit = false;
                if (gi < gj) {
                    float ep = 1.0f / (1.0f + expf(-acc[r][c]));
                    float P = ep / epmax;
                    float Pc = fminf(fmaxf(P, 1e-6f), 1.0f - 1e-6f);
                    float uu = u[(size_t)gi * NN + gj];
                    float ucv = fminf(fmaxf(uu, 1e-6f), 1.0f - 1e-6f);
                    bit = Pc > (1.0f - ucv);
                } else if (gi == gj) {
                    bit = true;
                }
                if (bit) {
                    atomicOr(&lm[li][lj >> 5], 1u << (lj & 31));
                    atomicOr(&lmT[lj][li >> 5], 1u << (li & 31));
                }
            }
        }
        __syncthreads();
        if (tid < 128) {
            int r = tid >> 1, wq = tid & 1;
            unsigned word = lm[r][wq];
            if (ti == tj) word |= lmT[r][wq];
            mb[(size_t)(ti * TS + r) * 128 + tj * 2 + wq] = word;
        } else if (ti != tj) {
            int r = (tid - 128) >> 1, wq = tid & 1;
            mb[(size_t)(tj * TS + r) * 128 + ti * 2 + wq] = lmT[r][wq];
        }
    }
}

// Pass 1 (S-store path): compute tile, store S to ws, fold into global max.
__global__ __launch_bounds__(256, 4) void k_stile_store(const float* __restrict__ h,
                                                        float* __restrict__ S,
                                                        unsigned* __restrict__ smax_key) {
    int ti = blockIdx.y, tj = blockIdx.x;
    if (tj < ti) return;
    __shared__ float Ah[TS][68];
    __shared__ float Bh[TS][68];
    int tid = threadIdx.x;
    int tx = tid & 15, ty = tid >> 4;
    const float* ha = h + (size_t)ti * TS * 128;
    const float* hb = h + (size_t)tj * TS * 128;

    float acc[4][4];
    #pragma unroll
    for (int r = 0; r < 4; ++r)
        #pragma unroll
        for (int c = 0; c < 4; ++c) acc[r][c] = 0.0f;

    for (int half = 0; half < 2; ++half) {
        __syncthreads();
        #pragma unroll
        for (int t = 0; t < 4; ++t) {
            int f = tid + t * 256;
            int row = f >> 4, kk = f & 15;
            *(float4*)&Ah[row][kk * 4] = *(const float4*)(ha + (size_t)row * 128 + half * 64 + kk * 4);
            *(float4*)&Bh[row][kk * 4] = *(const float4*)(hb + (size_t)row * 128 + half * 64 + kk * 4);
        }
        __syncthreads();
        #pragma unroll 2
        for (int k4 = 0; k4 < 16; ++k4) {
            float4 a[4], b[4];
            #pragma unroll
            for (int r = 0; r < 4; ++r) a[r] = *(const float4*)&Ah[ty + 16 * r][k4 * 4];
            #pragma unroll
            for (int c = 0; c < 4; ++c) b[c] = *(const float4*)&Bh[tx + 16 * c][k4 * 4];
            #pragma unroll
            for (int r = 0; r < 4; ++r)
                #pragma unroll
                for (int c = 0; c < 4; ++c) {
                    acc[r][c] = fmaf(a[r].x, b[c].x, acc[r][c]);
                    acc[r][c] = fmaf(a[r].y, b[c].y, acc[r][c]);
                    acc[r][c] = fmaf(a[r].z, b[c].z, acc[r][c]);
                    acc[r][c] = fmaf(a[r].w, b[c].w, acc[r][c]);
                }
        }
    }

    float* sp = S + (size_t)(ti * 64 + tj) * 4096;
    #pragma unroll
    for (int r = 0; r < 4; ++r)
        #pragma unroll
        for (int c = 0; c < 4; ++c)
            sp[(ty + 16 * r) * 64 + tx + 16 * c] = acc[r][c];

    float m = -3.4e38f;
    #pragma unroll
    for (int r = 0; r < 4; ++r)
        #pragma unroll
        for (int c = 0; c < 4; ++c) m = fmaxf(m, acc[r][c]);
    #pragma unroll
    for (int o = 1; o < 64; o <<= 1) m = fmaxf(m, __shfl_xor(m, o, 64));
    __shared__ float wm[4];
    if ((tid & 63) == 0) wm[tid >> 6] = m;
    __syncthreads();
    if (tid == 0)
        atomicMax(smax_key, fkey(fmaxf(fmaxf(wm[0], wm[1]), fmaxf(wm[2], wm[3]))));
}

// Pass 2 (S-store path): read stored S, emit mask bits.
__global__ __launch_bounds__(256, 4) void k_bitemit(const float* __restrict__ S,
                                                    const float* __restrict__ u,
                                                    const unsigned* __restrict__ smax_key,
                                                    unsigned* __restrict__ mb) {
    int ti = blockIdx.y, tj = blockIdx.x;
    if (tj < ti) return;
    int tid = threadIdx.x;
    int tx = tid & 15, ty = tid >> 4;
    float smax = funkey(*smax_key);
    float epmax = 1.0f / (1.0f + expf(-smax));
    __shared__ unsigned lm[TS][2];
    __shared__ unsigned lmT[TS][2];
    if (tid < 128) { lm[tid >> 1][tid & 1] = 0u; lmT[tid >> 1][tid & 1] = 0u; }
    __syncthreads();
    const float* sp = S + (size_t)(ti * 64 + tj) * 4096;
    #pragma unroll
    for (int r = 0; r < 4; ++r) {
        #pragma unroll
        for (int c = 0; c < 4; ++c) {
            int li = ty + 16 * r, lj = tx + 16 * c;
            int gi = ti * TS + li, gj = tj * TS + lj;
            bool bit = false;
            if (gi < gj) {
                float ep = 1.0f / (1.0f + expf(-sp[li * 64 + lj]));
                float P = ep / epmax;
                float Pc = fminf(fmaxf(P, 1e-6f), 1.0f - 1e-6f);
                float uu = u[(size_t)gi * NN + gj];
                float ucv = fminf(fmaxf(uu, 1e-6f), 1.0f - 1e-6f);
                bit = Pc > (1.0f - ucv);
            } else if (gi == gj) {
                bit = true;
            }
            if (bit) {
                atomicOr(&lm[li][lj >> 5], 1u << (lj & 31));
                atomicOr(&lmT[lj][li >> 5], 1u << (li & 31));
            }
        }
    }
    __syncthreads();
    if (tid < 128) {
        int r = tid >> 1, wq = tid & 1;
        unsigned word = lm[r][wq];
        if (ti == tj) word |= lmT[r][wq];
        mb[(size_t)(ti * TS + r) * 128 + tj * 2 + wq] = word;
    } else if (ti != tj) {
        int r = (tid - 128) >> 1, wq = tid & 1;
        mb[(size_t)(tj * TS + r) * 128 + ti * 2 + wq] = lmT[r][wq];
    }
}

// Masked max, D=256, partial-write merge (merged in downstream GEMM staging).
// RT=16 rows/block, JS=8 segments -> 2048 blocks = 8/CU (full occupancy).
// Wave-uniform mask via readfirstlane + scalar sext; and4 + v_max3 pairing.
template<int RT, int JS>
__global__ __launch_bounds__(256, 8) void k_mmax256(const unsigned* __restrict__ mb,
                                                    const float* __restrict__ z,
                                                    float* __restrict__ part) {
    constexpr int JPS = NN / JS;   // 512
    constexpr int WPS = JPS / 32;  // 16
    constexpr int RPG = RT / 4;    // 4
    constexpr int NRB = NN / RT;   // 256
    int rowblk = blockIdx.x % NRB, js = blockIdx.x / NRB;
    int i0 = rowblk * RT;

    __shared__ unsigned msk[RT][WPS + 1];
    {
        int t = threadIdx.x;           // RT*WPS == 256
        msk[t / WPS][t % WPS] = mb[(size_t)(i0 + t / WPS) * 128 + js * WPS + t % WPS];
    }
    __syncthreads();

    int d4 = threadIdx.x & 63;
    int g = threadIdx.x >> 6;
    const float4* zbase = (const float4*)z + (size_t)js * JPS * 64 + d4;

    float4 acc[RPG];
    #pragma unroll
    for (int r = 0; r < RPG; ++r) acc[r] = make_float4(0.f, 0.f, 0.f, 0.f);

    #pragma unroll 1
    for (int wq = 0; wq < WPS; ++wq) {
        unsigned m[RPG];
        #pragma unroll
        for (int r = 0; r < RPG; ++r)
            m[r] = (unsigned)__builtin_amdgcn_readfirstlane((int)msk[g * RPG + r][wq]);
        const float4* zp = zbase + (size_t)(wq * 32) * 64;
        #pragma unroll 2
        for (int j4 = 0; j4 < 32; j4 += 4) {
            float4 z0 = zp[0 * 64];
            float4 z1 = zp[1 * 64];
            float4 z2 = zp[2 * 64];
            float4 z3 = zp[3 * 64];
            #pragma unroll
            for (int r = 0; r < RPG; ++r) {
                unsigned s0 = bit_sext_s(m[r], j4 + 0);
                unsigned s1 = bit_sext_s(m[r], j4 + 1);
                unsigned s2 = bit_sext_s(m[r], j4 + 2);
                unsigned s3 = bit_sext_s(m[r], j4 + 3);
                acc[r] = max3_4(acc[r], and4(s0, z0), and4(s1, z1));
                acc[r] = max3_4(acc[r], and4(s2, z2), and4(s3, z3));
            }
            zp += 4 * 64;
        }
    }

    float4* po = (float4*)(part + (size_t)js * NN * 256);
    #pragma unroll
    for (int r = 0; r < RPG; ++r)
        po[(size_t)(i0 + g * RPG + r) * 64 + d4] = acc[r];
}

// Masked max, D=128, partial-write merge. Wave covers 2 j's (jpar = lane>>5).
template<int RT, int JS>
__global__ __launch_bounds__(256, 8) void k_mmax128(const unsigned* __restrict__ mb,
                                                    const float* __restrict__ z,
                                                    float* __restrict__ part) {
    constexpr int JPS = NN / JS;   // 512
    constexpr int WPS = JPS / 32;  // 16
    constexpr int RPG = RT / 4;    // 4
    constexpr int NRB = NN / RT;   // 256
    int rowblk = blockIdx.x % NRB, js = blockIdx.x / NRB;
    int i0 = rowblk * RT;

    __shared__ unsigned msk[RT][WPS + 1];
    {
        int t = threadIdx.x;
        msk[t / WPS][t % WPS] = mb[(size_t)(i0 + t / WPS) * 128 + js * WPS + t % WPS];
    }
    __syncthreads();

    int lane = threadIdx.x & 63;
    int g = threadIdx.x >> 6;
    unsigned jpar = lane >> 5;
    int d4 = lane & 31;
    const float4* zbase = (const float4*)z + (size_t)js * JPS * 32 + d4;

    float4 acc[RPG];
    #pragma unroll
    for (int r = 0; r < RPG; ++r) acc[r] = make_float4(0.f, 0.f, 0.f, 0.f);

    #pragma unroll 1
    for (int wq = 0; wq < WPS; ++wq) {
        unsigned m[RPG];
        #pragma unroll
        for (int r = 0; r < RPG; ++r) m[r] = msk[g * RPG + r][wq];
        const float4* zp = zbase + (size_t)(wq * 32) * 32;
        #pragma unroll 2
        for (int j4 = 0; j4 < 32; j4 += 4) {
            float4 za = zp[(size_t)jpar * 32];
            float4 zb = zp[(size_t)(2 + jpar) * 32];
            unsigned oa = j4 + jpar, ob = j4 + 2 + jpar;
            #pragma unroll
            for (int r = 0; r < RPG; ++r) {
                unsigned sa = bit_sext(m[r], oa);
                unsigned sb = bit_sext(m[r], ob);
                acc[r] = max3_4(acc[r], and4(sa, za), and4(sb, zb));
            }
            zp += 4 * 32;
        }
    }

    #pragma unroll
    for (int r = 0; r < RPG; ++r) {
        acc[r].x = fmaxf(acc[r].x, __shfl_xor(acc[r].x, 32, 64));
        acc[r].y = fmaxf(acc[r].y, __shfl_xor(acc[r].y, 32, 64));
        acc[r].z = fmaxf(acc[r].z, __shfl_xor(acc[r].z, 32, 64));
        acc[r].w = fmaxf(acc[r].w, __shfl_xor(acc[r].w, 32, 64));
    }
    if (!jpar) {
        float4* po = (float4*)(part + (size_t)js * NN * 128);
        #pragma unroll
        for (int r = 0; r < RPG; ++r)
            po[(size_t)(i0 + g * RPG + r) * 32 + d4] = acc[r];
    }
}

__global__ void k_relu_l2norm(float* __restrict__ h) {
    int i = blockIdx.x, d = threadIdx.x;
    float v = fmaxf(h[(size_t)i * 128 + d], 0.0f);
    float ss = v * v;
    #pragma unroll
    for (int o = 1; o < 64; o <<= 1) ss += __shfl_xor(ss, o, 64);
    __shared__ float w2[2];
    if ((d & 63) == 0) w2[d >> 6] = ss;
    __syncthreads();
    float tot = w2[0] + w2[1];
    float denom = fmaxf(sqrtf(tot), 1e-12f);
    h[(size_t)i * 128 + d] = v / denom;
}

// Final 128->32 GEMM with NS-way partial merge, LDS-staged. 4 rows per block.
template<int NS>
__global__ void k_gemm_final(const float* __restrict__ X, size_t xstride,
                             const float* __restrict__ W,
                             const float* __restrict__ b1, const float* __restrict__ b2,
                             float* __restrict__ out) {
    __shared__ float xr[4][128];
    int i0 = blockIdx.x * 4;
    for (int t = threadIdx.x; t < 512; t += 128) {
        int r = t >> 7, k = t & 127;
        float v = X[(size_t)(i0 + r) * 128 + k];
        #pragma unroll
        for (int s = 1; s < NS; ++s)
            v = fmaxf(v, X[(size_t)s * xstride + (size_t)(i0 + r) * 128 + k]);
        xr[r][k] = v;
    }
    __syncthreads();
    int il = threadIdx.x >> 5, j = threadIdx.x & 31;
    float acc = 0.0f;
    #pragma unroll 8
    for (int k = 0; k < 128; ++k) acc = fmaf(xr[il][k], W[k * 32 + j], acc);
    out[(size_t)(i0 + il) * 32 + j] = acc + b1[j] + b2[j];
}

extern "C" void kernel_launch(void* const* d_in, const int* in_sizes, int n_in,
                              void* d_out, int out_size, void* d_ws, size_t ws_size,
                              hipStream_t stream) {
    const float* inputs = (const float*)d_in[1];
    const float* feat   = (const float*)d_in[2];
    const float* u      = (const float*)d_in[3];
    const int*   src    = (const int*)d_in[4];
    const int*   dst    = (const int*)d_in[5];
    const float* gc0W = (const float*)d_in[6],  *gc0b = (const float*)d_in[7];
    const float* gc1W = (const float*)d_in[8],  *gc1b = (const float*)d_in[9];
    const float* p0W  = (const float*)d_in[10], *p0b  = (const float*)d_in[11];
    const float* l0W  = (const float*)d_in[12], *l0b  = (const float*)d_in[13];
    const float* b0   = (const float*)d_in[14];
    const float* p1W  = (const float*)d_in[15], *p1b  = (const float*)d_in[16];
    const float* l1W  = (const float*)d_in[17], *l1b  = (const float*)d_in[18];
    const float* b1   = (const float*)d_in[19];
    const float* p2W  = (const float*)d_in[20], *p2b  = (const float*)d_in[21];
    const float* l2W  = (const float*)d_in[22], *l2b  = (const float*)d_in[23];
    const float* b2   = (const float*)d_in[24];
    float* out = (float*)d_out;

    const size_t MB = 1048576;
    char* w = (char*)d_ws;
    int*      cnt_src  = (int*)(w + 0);            // 16 KB
    int*      cnt_dst  = (int*)(w + 16384);        // 16 KB
    float*    on       = (float*)(w + 32768);      // 16 KB
    float*    inn      = (float*)(w + 49152);      // 16 KB
    unsigned* smax_key = (unsigned*)(w + 65536);   // pad to 128 KB
    char*     big      = w + 131072;
    float*    tmp      = (float*)(big);            // 2 MB
    float*    agg      = (float*)(big + 2 * MB);   // 2 MB
    float*    hbuf     = (float*)(big + 4 * MB);   // 2 MB
    unsigned* mb       = (unsigned*)(big + 6 * MB);// 2 MB
    float*    z        = (float*)(big + 8 * MB);   // 4 MB
    float*    pm       = (float*)(big + 12 * MB);  // 32 MB (8 split partials)
    float*    hs       = (float*)(big + 44 * MB);  // 2 MB
    float*    Sbuf     = (float*)(big + 46 * MB);  // 64 MB
    bool use_sstore = ws_size >= 131072 + 110 * MB;

    hipMemsetAsync(w, 0, 131072, stream);
    k_count<<<EE / 256, 256, 0, stream>>>(src, dst, cnt_src, cnt_dst);
    k_norm<<<NN / 256, 256, 0, stream>>>(cnt_src, cnt_dst, on, inn);

    // --- GCN layer 0 ---
    k_gemm_scale<256, 128><<<NN, 128, 0, stream>>>(inputs, gc0W, on, tmp);
    hipMemsetAsync(agg, 0, (size_t)NN * 128 * 4, stream);
    k_scatter<<<EE, 128, 0, stream>>>(tmp, src, dst, agg);
    k_gcn_out<<<NN * 128 / 256, 256, 0, stream>>>(agg, inn, gc0b, hbuf, 1);

    // --- GCN layer 1 ---
    k_gemm_scale<128, 128><<<NN, 128, 0, stream>>>(hbuf, gc1W, on, tmp);
    hipMemsetAsync(agg, 0, (size_t)NN * 128 * 4, stream);
    k_scatter<<<EE, 128, 0, stream>>>(tmp, src, dst, agg);
    k_gcn_out<<<NN * 128 / 256, 256, 0, stream>>>(agg, inn, gc1b, hbuf, 0);

    // --- decode: S max + mask bits ---
    dim3 tg(64, 64);
    if (use_sstore) {
        k_stile_store<<<tg, 256, 0, stream>>>(hbuf, Sbuf, smax_key);
        k_bitemit<<<tg, 256, 0, stream>>>(Sbuf, u, smax_key, mb);
    } else {
        k_stile<0><<<tg, 256, 0, stream>>>(hbuf, nullptr, smax_key, nullptr);
        k_stile<1><<<tg, 256, 0, stream>>>(hbuf, u, smax_key, mb);
    }

    // --- GraphSAGE layer 0 (256 -> 128) ---
    k_gemm_mrg<256, 256, 1><<<NN, 256, 0, stream>>>(feat, 0, p0W, p0b, nullptr, z, 1);
    k_mmax256<16, 8><<<(NN / 16) * 8, 256, 0, stream>>>(mb, z, pm);
    k_gemm_mrg<256, 128, 8><<<NN, 128, 0, stream>>>(pm, (size_t)NN * 256, l0W, l0b, b0, hs, 0);
    k_relu_l2norm<<<NN, 128, 0, stream>>>(hs);

    // --- GraphSAGE layer 1 (128 -> 128) ---
    k_gemm_mrg<128, 128, 1><<<NN, 128, 0, stream>>>(hs, 0, p1W, p1b, nullptr, z, 1);
    k_mmax128<16, 8><<<(NN / 16) * 8, 256, 0, stream>>>(mb, z, pm);
    k_gemm_mrg<128, 128, 8><<<NN, 128, 0, stream>>>(pm, (size_t)NN * 128, l1W, l1b, b1, tmp, 0);
    k_relu_l2norm<<<NN, 128, 0, stream>>>(tmp);

    // --- GraphSAGE layer 2 (128 -> 32) ---
    k_gemm_mrg<128, 128, 1><<<NN, 128, 0, stream>>>(tmp, 0, p2W, p2b, nullptr, z, 1);
    k_mmax128<16, 8><<<(NN / 16) * 8, 256, 0, stream>>>(mb, z, pm);
    k_gemm_final<8><<<NN / 4, 128, 0, stream>>>(pm, (size_t)NN * 128, l2W, l2b, b2, out);
}

// Round 13
// 759.650 us; speedup vs baseline: 1.1780x; 1.0107x over previous
//
#include <hip/hip_runtime.h>
#include <cstdint>
#include <cstddef>

#define NN 4096
#define EE 131072
#define TS 64

__device__ __forceinline__ unsigned fkey(float f) {
    unsigned u = __float_as_uint(f);
    return (u & 0x80000000u) ? ~u : (u | 0x80000000u);
}
__device__ __forceinline__ float funkey(unsigned k) {
    unsigned u = (k & 0x80000000u) ? (k & 0x7fffffffu) : ~k;
    return __uint_as_float(u);
}

__device__ __forceinline__ float4 max3_4(float4 a, float4 b, float4 c) {
    return make_float4(fmaxf(fmaxf(a.x, b.x), c.x), fmaxf(fmaxf(a.y, b.y), c.y),
                       fmaxf(fmaxf(a.z, b.z), c.z), fmaxf(fmaxf(a.w, b.w), c.w));
}
__device__ __forceinline__ unsigned bit_sext(unsigned w, unsigned off) {
#if __has_builtin(__builtin_amdgcn_sbfe)
    return (unsigned)__builtin_amdgcn_sbfe((int)w, off, 1u);
#else
    return (unsigned)(-(int)((w >> off) & 1u));
#endif
}
__device__ __forceinline__ unsigned bit_sext_s(unsigned w, int off) {
    return (unsigned)(((int)(w << (31 - off))) >> 31);
}
__device__ __forceinline__ float4 and4(unsigned m, float4 v) {
    return make_float4(__uint_as_float(m & __float_as_uint(v.x)),
                       __uint_as_float(m & __float_as_uint(v.y)),
                       __uint_as_float(m & __float_as_uint(v.z)),
                       __uint_as_float(m & __float_as_uint(v.w)));
}

__global__ void k_count(const int* __restrict__ src, const int* __restrict__ dst,
                        int* __restrict__ cs, int* __restrict__ cd) {
    int e = blockIdx.x * 256 + threadIdx.x;
    if (e < EE) {
        atomicAdd(&cs[src[e]], 1);
        atomicAdd(&cd[dst[e]], 1);
    }
}

__global__ void k_norm(const int* __restrict__ cs, const int* __restrict__ cd,
                       float* __restrict__ on, float* __restrict__ inn) {
    int i = blockIdx.x * 256 + threadIdx.x;
    if (i < NN) {
        int a = cs[i] > 1 ? cs[i] : 1;
        int b = cd[i] > 1 ? cd[i] : 1;
        on[i]  = 1.0f / sqrtf((float)a);
        inn[i] = 1.0f / sqrtf((float)b);
    }
}

// RB rows per block: W[k][j] read once per block for RB rows (L2 traffic / RB).
template<int K, int ND, int RB>
__global__ void k_gemm_scale(const float* __restrict__ X, const float* __restrict__ W,
                             const float* __restrict__ scale, float* __restrict__ out) {
    __shared__ float xr[RB][K];
    int i0 = blockIdx.x * RB;
    for (int t = threadIdx.x; t < RB * K; t += ND)
        xr[t / K][t % K] = X[(size_t)(i0 + t / K) * K + t % K];
    __syncthreads();
    int j = threadIdx.x;
    float acc[RB];
    #pragma unroll
    for (int r = 0; r < RB; ++r) acc[r] = 0.0f;
    #pragma unroll 4
    for (int k = 0; k < K; ++k) {
        float w = W[k * ND + j];
        #pragma unroll
        for (int r = 0; r < RB; ++r) acc[r] = fmaf(xr[r][k], w, acc[r]);
    }
    #pragma unroll
    for (int r = 0; r < RB; ++r)
        out[(size_t)(i0 + r) * ND + j] = acc[r] * scale[i0 + r];
}

// out = (max over NS split-partials of X) @ W + b1 (+b2) (opt relu), RB rows/block.
template<int K, int ND, int NS, int RB>
__global__ void k_gemm_mrg(const float* __restrict__ X, size_t xstride,
                           const float* __restrict__ W,
                           const float* __restrict__ b1, const float* __restrict__ b2,
                           float* __restrict__ out, int do_relu) {
    __shared__ float xr[RB][K];
    int i0 = blockIdx.x * RB;
    for (int t = threadIdx.x; t < RB * K; t += ND) {
        size_t off = (size_t)(i0 + t / K) * K + t % K;
        float v = X[off];
        #pragma unroll
        for (int s = 1; s < NS; ++s) v = fmaxf(v, X[(size_t)s * xstride + off]);
        xr[t / K][t % K] = v;
    }
    __syncthreads();
    int j = threadIdx.x;
    float acc[RB];
    #pragma unroll
    for (int r = 0; r < RB; ++r) acc[r] = 0.0f;
    #pragma unroll 4
    for (int k = 0; k < K; ++k) {
        float w = W[k * ND + j];
        #pragma unroll
        for (int r = 0; r < RB; ++r) acc[r] = fmaf(xr[r][k], w, acc[r]);
    }
    #pragma unroll
    for (int r = 0; r < RB; ++r) {
        float v = acc[r] + b1[j];
        if (b2) v += b2[j];
        if (do_relu) v = fmaxf(v, 0.0f);
        out[(size_t)(i0 + r) * ND + j] = v;
    }
}

__global__ void k_scatter(const float* __restrict__ t, const int* __restrict__ src,
                          const int* __restrict__ dst, float* __restrict__ agg) {
    int e = blockIdx.x;
    int j = threadIdx.x;   // 128 threads
    int s = src[e], d = dst[e];
    atomicAdd(&agg[(size_t)d * 128 + j], t[(size_t)s * 128 + j]);
}

__global__ void k_gcn_out(const float* __restrict__ agg, const float* __restrict__ inn,
                          const float* __restrict__ b, float* __restrict__ out, int do_relu) {
    int idx = blockIdx.x * 256 + threadIdx.x;
    int i = idx >> 7, j = idx & 127;
    float v = agg[idx] * inn[i] + b[j];
    if (do_relu) v = fmaxf(v, 0.0f);
    out[idx] = v;
}

// ---- S = h h^T 64x64 tile; MODE 0: max-only; MODE 1: recompute + bit-emit ----
template<int MODE>
__global__ __launch_bounds__(256, 4) void k_stile(const float* __restrict__ h,
                                                  const float* __restrict__ u,
                                                  unsigned* __restrict__ smax_key,
                                                  unsigned* __restrict__ mb) {
    int ti = blockIdx.y, tj = blockIdx.x;
    if (tj < ti) return;
    __shared__ float Ah[TS][68];
    __shared__ float Bh[TS][68];
    int tid = threadIdx.x;
    int tx = tid & 15, ty = tid >> 4;
    const float* ha = h + (size_t)ti * TS * 128;
    const float* hb = h + (size_t)tj * TS * 128;

    float acc[4][4];
    #pragma unroll
    for (int r = 0; r < 4; ++r)
        #pragma unroll
        for (int c = 0; c < 4; ++c) acc[r][c] = 0.0f;

    for (int half = 0; half < 2; ++half) {
        __syncthreads();
        #pragma unroll
        for (int t = 0; t < 4; ++t) {
            int f = tid + t * 256;
            int row = f >> 4, kk = f & 15;
            *(float4*)&Ah[row][kk * 4] = *(const float4*)(ha + (size_t)row * 128 + half * 64 + kk * 4);
            *(float4*)&Bh[row][kk * 4] = *(const float4*)(hb + (size_t)row * 128 + half * 64 + kk * 4);
        }
        __syncthreads();
        #pragma unroll 2
        for (int k4 = 0; k4 < 16; ++k4) {
            float4 a[4], b[4];
            #pragma unroll
            for (int r = 0; r < 4; ++r) a[r] = *(const float4*)&Ah[ty + 16 * r][k4 * 4];
            #pragma unroll
            for (int c = 0; c < 4; ++c) b[c] = *(const float4*)&Bh[tx + 16 * c][k4 * 4];
            #pragma unroll
            for (int r = 0; r < 4; ++r)
                #pragma unroll
                for (int c = 0; c < 4; ++c) {
                    acc[r][c] = fmaf(a[r].x, b[c].x, acc[r][c]);
                    acc[r][c] = fmaf(a[r].y, b[c].y, acc[r][c]);
                    acc[r][c] = fmaf(a[r].z, b[c].z, acc[r][c]);
                    acc[r][c] = fmaf(a[r].w, b[c].w, acc[r][c]);
                }
        }
    }

    if constexpr (MODE == 0) {
        float m = -3.4e38f;
        #pragma unroll
        for (int r = 0; r < 4; ++r)
            #pragma unroll
            for (int c = 0; c < 4; ++c) m = fmaxf(m, acc[r][c]);
        #pragma unroll
        for (int o = 1; o < 64; o <<= 1) m = fmaxf(m, __shfl_xor(m, o, 64));
        __shared__ float wm[4];
        if ((tid & 63) == 0) wm[tid >> 6] = m;
        __syncthreads();
        if (tid == 0) {
            float mm = fmaxf(fmaxf(wm[0], wm[1]), fmaxf(wm[2], wm[3]));
            atomicMax(smax_key, fkey(mm));
        }
    } else {
        float smax = funkey(*smax_key);
        float epmax = 1.0f / (1.0f + expf(-smax));
        __shared__ unsigned lm[TS][2];
        __shared__ unsigned lmT[TS][2];
        if (tid < 128) { lm[tid >> 1][tid & 1] = 0u; lmT[tid >> 1][tid & 1] = 0u; }
        __syncthreads();
        #pragma unroll
        for (int r = 0; r < 4; ++r) {
            #pragma unroll
            for (int c = 0; c < 4; ++c) {
                int li = ty + 16 * r, lj = tx + 16 * c;
                int gi = ti * TS + li, gj = tj * TS + lj;
                bool bit = false;
                if (gi < gj) {
                    float ep = 1.0f / (1.0f + expf(-acc[r][c]));
                    float P = ep / epmax;
                    float Pc = fminf(fmaxf(P, 1e-6f), 1.0f - 1e-6f);
                    float uu = u[(size_t)gi * NN + gj];
                    float ucv = fminf(fmaxf(uu, 1e-6f), 1.0f - 1e-6f);
                    bit = Pc > (1.0f - ucv);
                } else if (gi == gj) {
                    bit = true;
                }
                if (bit) {
                    atomicOr(&lm[li][lj >> 5], 1u << (lj & 31));
                    atomicOr(&lmT[lj][li >> 5], 1u << (li & 31));
                }
            }
        }
        __syncthreads();
        if (tid < 128) {
            int r = tid >> 1, wq = tid & 1;
            unsigned word = lm[r][wq];
            if (ti == tj) word |= lmT[r][wq];
            mb[(size_t)(ti * TS + r) * 128 + tj * 2 + wq] = word;
        } else if (ti != tj) {
            int r = (tid - 128) >> 1, wq = tid & 1;
            mb[(size_t)(tj * TS + r) * 128 + ti * 2 + wq] = lmT[r][wq];
        }
    }
}

// Pass 1 (S-store path): compute tile, store S to ws, fold into global max.
__global__ __launch_bounds__(256, 4) void k_stile_store(const float* __restrict__ h,
                                                        float* __restrict__ S,
                                                        unsigned* __restrict__ smax_key) {
    int ti = blockIdx.y, tj = blockIdx.x;
    if (tj < ti) return;
    __shared__ float Ah[TS][68];
    __shared__ float Bh[TS][68];
    int tid = threadIdx.x;
    int tx = tid & 15, ty = tid >> 4;
    const float* ha = h + (size_t)ti * TS * 128;
    const float* hb = h + (size_t)tj * TS * 128;

    float acc[4][4];
    #pragma unroll
    for (int r = 0; r < 4; ++r)
        #pragma unroll
        for (int c = 0; c < 4; ++c) acc[r][c] = 0.0f;

    for (int half = 0; half < 2; ++half) {
        __syncthreads();
        #pragma unroll
        for (int t = 0; t < 4; ++t) {
            int f = tid + t * 256;
            int row = f >> 4, kk = f & 15;
            *(float4*)&Ah[row][kk * 4] = *(const float4*)(ha + (size_t)row * 128 + half * 64 + kk * 4);
            *(float4*)&Bh[row][kk * 4] = *(const float4*)(hb + (size_t)row * 128 + half * 64 + kk * 4);
        }
        __syncthreads();
        #pragma unroll 2
        for (int k4 = 0; k4 < 16; ++k4) {
            float4 a[4], b[4];
            #pragma unroll
            for (int r = 0; r < 4; ++r) a[r] = *(const float4*)&Ah[ty + 16 * r][k4 * 4];
            #pragma unroll
            for (int c = 0; c < 4; ++c) b[c] = *(const float4*)&Bh[tx + 16 * c][k4 * 4];
            #pragma unroll
            for (int r = 0; r < 4; ++r)
                #pragma unroll
                for (int c = 0; c < 4; ++c) {
                    acc[r][c] = fmaf(a[r].x, b[c].x, acc[r][c]);
                    acc[r][c] = fmaf(a[r].y, b[c].y, acc[r][c]);
                    acc[r][c] = fmaf(a[r].z, b[c].z, acc[r][c]);
                    acc[r][c] = fmaf(a[r].w, b[c].w, acc[r][c]);
                }
        }
    }

    float* sp = S + (size_t)(ti * 64 + tj) * 4096;
    #pragma unroll
    for (int r = 0; r < 4; ++r)
        #pragma unroll
        for (int c = 0; c < 4; ++c)
            sp[(ty + 16 * r) * 64 + tx + 16 * c] = acc[r][c];

    float m = -3.4e38f;
    #pragma unroll
    for (int r = 0; r < 4; ++r)
        #pragma unroll
        for (int c = 0; c < 4; ++c) m = fmaxf(m, acc[r][c]);
    #pragma unroll
    for (int o = 1; o < 64; o <<= 1) m = fmaxf(m, __shfl_xor(m, o, 64));
    __shared__ float wm[4];
    if ((tid & 63) == 0) wm[tid >> 6] = m;
    __syncthreads();
    if (tid == 0)
        atomicMax(smax_key, fkey(fmaxf(fmaxf(wm[0], wm[1]), fmaxf(wm[2], wm[3]))));
}

// Pass 2 (S-store path): read stored S, emit mask bits.
__global__ __launch_bounds__(256, 4) void k_bitemit(const float* __restrict__ S,
                                                    const float* __restrict__ u,
                                                    const unsigned* __restrict__ smax_key,
                                                    unsigned* __restrict__ mb) {
    int ti = blockIdx.y, tj = blockIdx.x;
    if (tj < ti) return;
    int tid = threadIdx.x;
    int tx = tid & 15, ty = tid >> 4;
    float smax = funkey(*smax_key);
    float epmax = 1.0f / (1.0f + expf(-smax));
    __shared__ unsigned lm[TS][2];
    __shared__ unsigned lmT[TS][2];
    if (tid < 128) { lm[tid >> 1][tid & 1] = 0u; lmT[tid >> 1][tid & 1] = 0u; }
    __syncthreads();
    const float* sp = S + (size_t)(ti * 64 + tj) * 4096;
    #pragma unroll
    for (int r = 0; r < 4; ++r) {
        #pragma unroll
        for (int c = 0; c < 4; ++c) {
            int li = ty + 16 * r, lj = tx + 16 * c;
            int gi = ti * TS + li, gj = tj * TS + lj;
            bool bit = false;
            if (gi < gj) {
                float ep = 1.0f / (1.0f + expf(-sp[li * 64 + lj]));
                float P = ep / epmax;
                float Pc = fminf(fmaxf(P, 1e-6f), 1.0f - 1e-6f);
                float uu = u[(size_t)gi * NN + gj];
                float ucv = fminf(fmaxf(uu, 1e-6f), 1.0f - 1e-6f);
                bit = Pc > (1.0f - ucv);
            } else if (gi == gj) {
                bit = true;
            }
            if (bit) {
                atomicOr(&lm[li][lj >> 5], 1u << (lj & 31));
                atomicOr(&lmT[lj][li >> 5], 1u << (li & 31));
            }
        }
    }
    __syncthreads();
    if (tid < 128) {
        int r = tid >> 1, wq = tid & 1;
        unsigned word = lm[r][wq];
        if (ti == tj) word |= lmT[r][wq];
        mb[(size_t)(ti * TS + r) * 128 + tj * 2 + wq] = word;
    } else if (ti != tj) {
        int r = (tid - 128) >> 1, wq = tid & 1;
        mb[(size_t)(tj * TS + r) * 128 + ti * 2 + wq] = lmT[r][wq];
    }
}

// Masked max, D=256, partial-write merge. RT=16 rows/block, JS=8 segments
// -> 2048 blocks = 8/CU (full occupancy). Wave-uniform mask via readfirstlane
// + scalar sext; and4 + max3 pairing (C++ only; round-11 proven codegen).
template<int RT, int JS>
__global__ __launch_bounds__(256, 8) void k_mmax256(const unsigned* __restrict__ mb,
                                                    const float* __restrict__ z,
                                                    float* __restrict__ part) {
    constexpr int JPS = NN / JS;   // 512
    constexpr int WPS = JPS / 32;  // 16
    constexpr int RPG = RT / 4;    // 4
    constexpr int NRB = NN / RT;   // 256
    int rowblk = blockIdx.x % NRB, js = blockIdx.x / NRB;
    int i0 = rowblk * RT;

    __shared__ unsigned msk[RT][WPS + 1];
    {
        int t = threadIdx.x;           // RT*WPS == 256
        msk[t / WPS][t % WPS] = mb[(size_t)(i0 + t / WPS) * 128 + js * WPS + t % WPS];
    }
    __syncthreads();

    int d4 = threadIdx.x & 63;
    int g = threadIdx.x >> 6;
    const float4* zbase = (const float4*)z + (size_t)js * JPS * 64 + d4;

    float4 acc[RPG];
    #pragma unroll
    for (int r = 0; r < RPG; ++r) acc[r] = make_float4(0.f, 0.f, 0.f, 0.f);

    #pragma unroll 1
    for (int wq = 0; wq < WPS; ++wq) {
        unsigned m[RPG];
        #pragma unroll
        for (int r = 0; r < RPG; ++r)
            m[r] = (unsigned)__builtin_amdgcn_readfirstlane((int)msk[g * RPG + r][wq]);
        const float4* zp = zbase + (size_t)(wq * 32) * 64;
        #pragma unroll 2
        for (int j4 = 0; j4 < 32; j4 += 4) {
            float4 z0 = zp[0 * 64];
            float4 z1 = zp[1 * 64];
            float4 z2 = zp[2 * 64];
            float4 z3 = zp[3 * 64];
            #pragma unroll
            for (int r = 0; r < RPG; ++r) {
                unsigned s0 = bit_sext_s(m[r], j4 + 0);
                unsigned s1 = bit_sext_s(m[r], j4 + 1);
                unsigned s2 = bit_sext_s(m[r], j4 + 2);
                unsigned s3 = bit_sext_s(m[r], j4 + 3);
                acc[r] = max3_4(acc[r], and4(s0, z0), and4(s1, z1));
                acc[r] = max3_4(acc[r], and4(s2, z2), and4(s3, z3));
            }
            zp += 4 * 64;
        }
    }

    float4* po = (float4*)(part + (size_t)js * NN * 256);
    #pragma unroll
    for (int r = 0; r < RPG; ++r)
        po[(size_t)(i0 + g * RPG + r) * 64 + d4] = acc[r];
}

// Masked max, D=128, partial-write merge. Wave covers 2 j's (jpar = lane>>5).
template<int RT, int JS>
__global__ __launch_bounds__(256, 8) void k_mmax128(const unsigned* __restrict__ mb,
                                                    const float* __restrict__ z,
                                                    float* __restrict__ part) {
    constexpr int JPS = NN / JS;   // 512
    constexpr int WPS = JPS / 32;  // 16
    constexpr int RPG = RT / 4;    // 4
    constexpr int NRB = NN / RT;   // 256
    int rowblk = blockIdx.x % NRB, js = blockIdx.x / NRB;
    int i0 = rowblk * RT;

    __shared__ unsigned msk[RT][WPS + 1];
    {
        int t = threadIdx.x;
        msk[t / WPS][t % WPS] = mb[(size_t)(i0 + t / WPS) * 128 + js * WPS + t % WPS];
    }
    __syncthreads();

    int lane = threadIdx.x & 63;
    int g = threadIdx.x >> 6;
    unsigned jpar = lane >> 5;
    int d4 = lane & 31;
    const float4* zbase = (const float4*)z + (size_t)js * JPS * 32 + d4;

    float4 acc[RPG];
    #pragma unroll
    for (int r = 0; r < RPG; ++r) acc[r] = make_float4(0.f, 0.f, 0.f, 0.f);

    #pragma unroll 1
    for (int wq = 0; wq < WPS; ++wq) {
        unsigned m[RPG];
        #pragma unroll
        for (int r = 0; r < RPG; ++r) m[r] = msk[g * RPG + r][wq];
        const float4* zp = zbase + (size_t)(wq * 32) * 32;
        #pragma unroll 2
        for (int j4 = 0; j4 < 32; j4 += 4) {
            float4 za = zp[(size_t)jpar * 32];
            float4 zb = zp[(size_t)(2 + jpar) * 32];
            unsigned oa = j4 + jpar, ob = j4 + 2 + jpar;
            #pragma unroll
            for (int r = 0; r < RPG; ++r) {
                unsigned sa = bit_sext(m[r], oa);
                unsigned sb = bit_sext(m[r], ob);
                acc[r] = max3_4(acc[r], and4(sa, za), and4(sb, zb));
            }
            zp += 4 * 32;
        }
    }

    #pragma unroll
    for (int r = 0; r < RPG; ++r) {
        acc[r].x = fmaxf(acc[r].x, __shfl_xor(acc[r].x, 32, 64));
        acc[r].y = fmaxf(acc[r].y, __shfl_xor(acc[r].y, 32, 64));
        acc[r].z = fmaxf(acc[r].z, __shfl_xor(acc[r].z, 32, 64));
        acc[r].w = fmaxf(acc[r].w, __shfl_xor(acc[r].w, 32, 64));
    }
    if (!jpar) {
        float4* po = (float4*)(part + (size_t)js * NN * 128);
        #pragma unroll
        for (int r = 0; r < RPG; ++r)
            po[(size_t)(i0 + g * RPG + r) * 32 + d4] = acc[r];
    }
}

__global__ void k_relu_l2norm(float* __restrict__ h) {
    int i = blockIdx.x, d = threadIdx.x;
    float v = fmaxf(h[(size_t)i * 128 + d], 0.0f);
    float ss = v * v;
    #pragma unroll
    for (int o = 1; o < 64; o <<= 1) ss += __shfl_xor(ss, o, 64);
    __shared__ float w2[2];
    if ((d & 63) == 0) w2[d >> 6] = ss;
    __syncthreads();
    float tot = w2[0] + w2[1];
    float denom = fmaxf(sqrtf(tot), 1e-12f);
    h[(size_t)i * 128 + d] = v / denom;
}

// Final 128->32 GEMM with NS-way partial merge, LDS-staged. 4 rows per block.
template<int NS>
__global__ void k_gemm_final(const float* __restrict__ X, size_t xstride,
                             const float* __restrict__ W,
                             const float* __restrict__ b1, const float* __restrict__ b2,
                             float* __restrict__ out) {
    __shared__ float xr[4][128];
    int i0 = blockIdx.x * 4;
    for (int t = threadIdx.x; t < 512; t += 128) {
        int r = t >> 7, k = t & 127;
        float v = X[(size_t)(i0 + r) * 128 + k];
        #pragma unroll
        for (int s = 1; s < NS; ++s)
            v = fmaxf(v, X[(size_t)s * xstride + (size_t)(i0 + r) * 128 + k]);
        xr[r][k] = v;
    }
    __syncthreads();
    int il = threadIdx.x >> 5, j = threadIdx.x & 31;
    float acc = 0.0f;
    #pragma unroll 8
    for (int k = 0; k < 128; ++k) acc = fmaf(xr[il][k], W[k * 32 + j], acc);
    out[(size_t)(i0 + il) * 32 + j] = acc + b1[j] + b2[j];
}

extern "C" void kernel_launch(void* const* d_in, const int* in_sizes, int n_in,
                              void* d_out, int out_size, void* d_ws, size_t ws_size,
                              hipStream_t stream) {
    const float* inputs = (const float*)d_in[1];
    const float* feat   = (const float*)d_in[2];
    const float* u      = (const float*)d_in[3];
    const int*   src    = (const int*)d_in[4];
    const int*   dst    = (const int*)d_in[5];
    const float* gc0W = (const float*)d_in[6],  *gc0b = (const float*)d_in[7];
    const float* gc1W = (const float*)d_in[8],  *gc1b = (const float*)d_in[9];
    const float* p0W  = (const float*)d_in[10], *p0b  = (const float*)d_in[11];
    const float* l0W  = (const float*)d_in[12], *l0b  = (const float*)d_in[13];
    const float* b0   = (const float*)d_in[14];
    const float* p1W  = (const float*)d_in[15], *p1b  = (const float*)d_in[16];
    const float* l1W  = (const float*)d_in[17], *l1b  = (const float*)d_in[18];
    const float* b1   = (const float*)d_in[19];
    const float* p2W  = (const float*)d_in[20], *p2b  = (const float*)d_in[21];
    const float* l2W  = (const float*)d_in[22], *l2b  = (const float*)d_in[23];
    const float* b2   = (const float*)d_in[24];
    float* out = (float*)d_out;

    const size_t MB = 1048576;
    char* w = (char*)d_ws;
    int*      cnt_src  = (int*)(w + 0);            // 16 KB
    int*      cnt_dst  = (int*)(w + 16384);        // 16 KB
    float*    on       = (float*)(w + 32768);      // 16 KB
    float*    inn      = (float*)(w + 49152);      // 16 KB
    unsigned* smax_key = (unsigned*)(w + 65536);   // pad to 128 KB
    char*     big      = w + 131072;
    float*    tmp      = (float*)(big);            // 2 MB
    float*    agg      = (float*)(big + 2 * MB);   // 2 MB
    float*    hbuf     = (float*)(big + 4 * MB);   // 2 MB
    unsigned* mb       = (unsigned*)(big + 6 * MB);// 2 MB
    float*    z        = (float*)(big + 8 * MB);   // 4 MB
    float*    pm       = (float*)(big + 12 * MB);  // 32 MB (8 split partials)
    float*    hs       = (float*)(big + 44 * MB);  // 2 MB
    float*    Sbuf     = (float*)(big + 46 * MB);  // 64 MB
    bool use_sstore = ws_size >= 131072 + 110 * MB;

    hipMemsetAsync(w, 0, 131072, stream);
    k_count<<<EE / 256, 256, 0, stream>>>(src, dst, cnt_src, cnt_dst);
    k_norm<<<NN / 256, 256, 0, stream>>>(cnt_src, cnt_dst, on, inn);

    // --- GCN layer 0 ---
    k_gemm_scale<256, 128, 4><<<NN / 4, 128, 0, stream>>>(inputs, gc0W, on, tmp);
    hipMemsetAsync(agg, 0, (size_t)NN * 128 * 4, stream);
    k_scatter<<<EE, 128, 0, stream>>>(tmp, src, dst, agg);
    k_gcn_out<<<NN * 128 / 256, 256, 0, stream>>>(agg, inn, gc0b, hbuf, 1);

    // --- GCN layer 1 ---
    k_gemm_scale<128, 128, 4><<<NN / 4, 128, 0, stream>>>(hbuf, gc1W, on, tmp);
    hipMemsetAsync(agg, 0, (size_t)NN * 128 * 4, stream);
    k_scatter<<<EE, 128, 0, stream>>>(tmp, src, dst, agg);
    k_gcn_out<<<NN * 128 / 256, 256, 0, stream>>>(agg, inn, gc1b, hbuf, 0);

    // --- decode: S max + mask bits ---
    dim3 tg(64, 64);
    if (use_sstore) {
        k_stile_store<<<tg, 256, 0, stream>>>(hbuf, Sbuf, smax_key);
        k_bitemit<<<tg, 256, 0, stream>>>(Sbuf, u, smax_key, mb);
    } else {
        k_stile<0><<<tg, 256, 0, stream>>>(hbuf, nullptr, smax_key, nullptr);
        k_stile<1><<<tg, 256, 0, stream>>>(hbuf, u, smax_key, mb);
    }

    // --- GraphSAGE layer 0 (256 -> 128) ---
    k_gemm_mrg<256, 256, 1, 4><<<NN / 4, 256, 0, stream>>>(feat, 0, p0W, p0b, nullptr, z, 1);
    k_mmax256<16, 8><<<(NN / 16) * 8, 256, 0, stream>>>(mb, z, pm);
    k_gemm_mrg<256, 128, 8, 4><<<NN / 4, 128, 0, stream>>>(pm, (size_t)NN * 256, l0W, l0b, b0, hs, 0);
    k_relu_l2norm<<<NN, 128, 0, stream>>>(hs);

    // --- GraphSAGE layer 1 (128 -> 128) ---
    k_gemm_mrg<128, 128, 1, 4><<<NN / 4, 128, 0, stream>>>(hs, 0, p1W, p1b, nullptr, z, 1);
    k_mmax128<16, 8><<<(NN / 16) * 8, 256, 0, stream>>>(mb, z, pm);
    k_gemm_mrg<128, 128, 8, 4><<<NN / 4, 128, 0, stream>>>(pm, (size_t)NN * 128, l1W, l1b, b1, tmp, 0);
    k_relu_l2norm<<<NN, 128, 0, stream>>>(tmp);

    // --- GraphSAGE layer 2 (128 -> 32) ---
    k_gemm_mrg<128, 128, 1, 4><<<NN / 4, 128, 0, stream>>>(tmp, 0, p2W, p2b, nullptr, z, 1);
    k_mmax128<16, 8><<<(NN / 16) * 8, 256, 0, stream>>>(mb, z, pm);
    k_gemm_final<8><<<NN / 4, 128, 0, stream>>>(pm, (size_t)NN * 128, l2W, l2b, b2, out);
}

// Round 14
// 757.215 us; speedup vs baseline: 1.1818x; 1.0032x over previous
//
#include <hip/hip_runtime.h>
#include <cstdint>
#include <cstddef>

#define NN 4096
#define EE 131072
#define TS 64

__device__ __forceinline__ unsigned fkey(float f) {
    unsigned u = __float_as_uint(f);
    return (u & 0x80000000u) ? ~u : (u | 0x80000000u);
}
__device__ __forceinline__ float funkey(unsigned k) {
    unsigned u = (k & 0x80000000u) ? (k & 0x7fffffffu) : ~k;
    return __uint_as_float(u);
}

// ---- VALU-only asm pins (no SALU, no SCC writes -> graph-capture safe) ----
// acc = max3(acc, b, c) pinned to v_max3_f32
__device__ __forceinline__ void max3v(float4& a, float4 b, float4 c) {
    asm("v_max3_f32 %0, %0, %1, %2" : "+v"(a.x) : "v"(b.x), "v"(c.x));
    asm("v_max3_f32 %0, %0, %1, %2" : "+v"(a.y) : "v"(b.y), "v"(c.y));
    asm("v_max3_f32 %0, %0, %1, %2" : "+v"(a.z) : "v"(b.z), "v"(c.z));
    asm("v_max3_f32 %0, %0, %1, %2" : "+v"(a.w) : "v"(b.w), "v"(c.w));
}
// v_and_b32 dst, s, v  (wave-uniform mask kept in SGPR)
__device__ __forceinline__ float4 andv_s(unsigned sm, float4 v) {
    float4 o;
    asm("v_and_b32 %0, %1, %2" : "=v"(o.x) : "s"(sm), "v"(v.x));
    asm("v_and_b32 %0, %1, %2" : "=v"(o.y) : "s"(sm), "v"(v.y));
    asm("v_and_b32 %0, %1, %2" : "=v"(o.z) : "s"(sm), "v"(v.z));
    asm("v_and_b32 %0, %1, %2" : "=v"(o.w) : "s"(sm), "v"(v.w));
    return o;
}
// v_and_b32 dst, v, v  (per-lane mask)
__device__ __forceinline__ float4 andv_v(unsigned vm, float4 v) {
    float4 o;
    asm("v_and_b32 %0, %1, %2" : "=v"(o.x) : "v"(vm), "v"(v.x));
    asm("v_and_b32 %0, %1, %2" : "=v"(o.y) : "v"(vm), "v"(v.y));
    asm("v_and_b32 %0, %1, %2" : "=v"(o.z) : "v"(vm), "v"(v.z));
    asm("v_and_b32 %0, %1, %2" : "=v"(o.w) : "v"(vm), "v"(v.w));
    return o;
}
// per-lane 1-bit sign-extended extract: v_bfe_i32 dst, s, v_off, 1
__device__ __forceinline__ unsigned vbfe1(unsigned m, unsigned off) {
    unsigned t;
    asm("v_bfe_i32 %0, %1, %2, 1" : "=v"(t) : "s"(m), "v"(off));
    return t;
}
// scalar-friendly sext-bit (C++; compiler emits SALU for uniform input)
__device__ __forceinline__ unsigned bit_sext_s(unsigned w, int off) {
    return (unsigned)(((int)(w << (31 - off))) >> 31);
}

__global__ void k_count(const int* __restrict__ src, const int* __restrict__ dst,
                        int* __restrict__ cs, int* __restrict__ cd) {
    int e = blockIdx.x * 256 + threadIdx.x;
    if (e < EE) {
        atomicAdd(&cs[src[e]], 1);
        atomicAdd(&cd[dst[e]], 1);
    }
}

__global__ void k_norm(const int* __restrict__ cs, const int* __restrict__ cd,
                       float* __restrict__ on, float* __restrict__ inn) {
    int i = blockIdx.x * 256 + threadIdx.x;
    if (i < NN) {
        int a = cs[i] > 1 ? cs[i] : 1;
        int b = cd[i] > 1 ? cd[i] : 1;
        on[i]  = 1.0f / sqrtf((float)a);
        inn[i] = 1.0f / sqrtf((float)b);
    }
}

// RB rows per block: W[k][j] read once per block for RB rows.
template<int K, int ND, int RB>
__global__ void k_gemm_scale(const float* __restrict__ X, const float* __restrict__ W,
                             const float* __restrict__ scale, float* __restrict__ out) {
    __shared__ float xr[RB][K];
    int i0 = blockIdx.x * RB;
    for (int t = threadIdx.x; t < RB * K; t += ND)
        xr[t / K][t % K] = X[(size_t)(i0 + t / K) * K + t % K];
    __syncthreads();
    int j = threadIdx.x;
    float acc[RB];
    #pragma unroll
    for (int r = 0; r < RB; ++r) acc[r] = 0.0f;
    #pragma unroll 4
    for (int k = 0; k < K; ++k) {
        float w = W[k * ND + j];
        #pragma unroll
        for (int r = 0; r < RB; ++r) acc[r] = fmaf(xr[r][k], w, acc[r]);
    }
    #pragma unroll
    for (int r = 0; r < RB; ++r)
        out[(size_t)(i0 + r) * ND + j] = acc[r] * scale[i0 + r];
}

// out = (max over NS split-partials of X) @ W + b1 (+b2) (opt relu), RB rows/block.
template<int K, int ND, int NS, int RB>
__global__ void k_gemm_mrg(const float* __restrict__ X, size_t xstride,
                           const float* __restrict__ W,
                           const float* __restrict__ b1, const float* __restrict__ b2,
                           float* __restrict__ out, int do_relu) {
    __shared__ float xr[RB][K];
    int i0 = blockIdx.x * RB;
    for (int t = threadIdx.x; t < RB * K; t += ND) {
        size_t off = (size_t)(i0 + t / K) * K + t % K;
        float v = X[off];
        #pragma unroll
        for (int s = 1; s < NS; ++s) v = fmaxf(v, X[(size_t)s * xstride + off]);
        xr[t / K][t % K] = v;
    }
    __syncthreads();
    int j = threadIdx.x;
    float acc[RB];
    #pragma unroll
    for (int r = 0; r < RB; ++r) acc[r] = 0.0f;
    #pragma unroll 4
    for (int k = 0; k < K; ++k) {
        float w = W[k * ND + j];
        #pragma unroll
        for (int r = 0; r < RB; ++r) acc[r] = fmaf(xr[r][k], w, acc[r]);
    }
    #pragma unroll
    for (int r = 0; r < RB; ++r) {
        float v = acc[r] + b1[j];
        if (b2) v += b2[j];
        if (do_relu) v = fmaxf(v, 0.0f);
        out[(size_t)(i0 + r) * ND + j] = v;
    }
}

__global__ void k_scatter(const float* __restrict__ t, const int* __restrict__ src,
                          const int* __restrict__ dst, float* __restrict__ agg) {
    int e = blockIdx.x;
    int j = threadIdx.x;   // 128 threads
    int s = src[e], d = dst[e];
    atomicAdd(&agg[(size_t)d * 128 + j], t[(size_t)s * 128 + j]);
}

__global__ void k_gcn_out(const float* __restrict__ agg, const float* __restrict__ inn,
                          const float* __restrict__ b, float* __restrict__ out, int do_relu) {
    int idx = blockIdx.x * 256 + threadIdx.x;
    int i = idx >> 7, j = idx & 127;
    float v = agg[idx] * inn[i] + b[j];
    if (do_relu) v = fmaxf(v, 0.0f);
    out[idx] = v;
}

// ---- S = h h^T 64x64 tile; MODE 0: max-only; MODE 1: recompute + bit-emit ----
template<int MODE>
__global__ __launch_bounds__(256, 4) void k_stile(const float* __restrict__ h,
                                                  const float* __restrict__ u,
                                                  unsigned* __restrict__ smax_key,
                                                  unsigned* __restrict__ mb) {
    int ti = blockIdx.y, tj = blockIdx.x;
    if (tj < ti) return;
    __shared__ float Ah[TS][68];
    __shared__ float Bh[TS][68];
    int tid = threadIdx.x;
    int tx = tid & 15, ty = tid >> 4;
    const float* ha = h + (size_t)ti * TS * 128;
    const float* hb = h + (size_t)tj * TS * 128;

    float acc[4][4];
    #pragma unroll
    for (int r = 0; r < 4; ++r)
        #pragma unroll
        for (int c = 0; c < 4; ++c) acc[r][c] = 0.0f;

    for (int half = 0; half < 2; ++half) {
        __syncthreads();
        #pragma unroll
        for (int t = 0; t < 4; ++t) {
            int f = tid + t * 256;
            int row = f >> 4, kk = f & 15;
            *(float4*)&Ah[row][kk * 4] = *(const float4*)(ha + (size_t)row * 128 + half * 64 + kk * 4);
            *(float4*)&Bh[row][kk * 4] = *(const float4*)(hb + (size_t)row * 128 + half * 64 + kk * 4);
        }
        __syncthreads();
        #pragma unroll 2
        for (int k4 = 0; k4 < 16; ++k4) {
            float4 a[4], b[4];
            #pragma unroll
            for (int r = 0; r < 4; ++r) a[r] = *(const float4*)&Ah[ty + 16 * r][k4 * 4];
            #pragma unroll
            for (int c = 0; c < 4; ++c) b[c] = *(const float4*)&Bh[tx + 16 * c][k4 * 4];
            #pragma unroll
            for (int r = 0; r < 4; ++r)
                #pragma unroll
                for (int c = 0; c < 4; ++c) {
                    acc[r][c] = fmaf(a[r].x, b[c].x, acc[r][c]);
                    acc[r][c] = fmaf(a[r].y, b[c].y, acc[r][c]);
                    acc[r][c] = fmaf(a[r].z, b[c].z, acc[r][c]);
                    acc[r][c] = fmaf(a[r].w, b[c].w, acc[r][c]);
                }
        }
    }

    if constexpr (MODE == 0) {
        float m = -3.4e38f;
        #pragma unroll
        for (int r = 0; r < 4; ++r)
            #pragma unroll
            for (int c = 0; c < 4; ++c) m = fmaxf(m, acc[r][c]);
        #pragma unroll
        for (int o = 1; o < 64; o <<= 1) m = fmaxf(m, __shfl_xor(m, o, 64));
        __shared__ float wm[4];
        if ((tid & 63) == 0) wm[tid >> 6] = m;
        __syncthreads();
        if (tid == 0) {
            float mm = fmaxf(fmaxf(wm[0], wm[1]), fmaxf(wm[2], wm[3]));
            atomicMax(smax_key, fkey(mm));
        }
    } else {
        float smax = funkey(*smax_key);
        float epmax = 1.0f / (1.0f + expf(-smax));
        __shared__ unsigned lm[TS][2];
        __shared__ unsigned lmT[TS][2];
        if (tid < 128) { lm[tid >> 1][tid & 1] = 0u; lmT[tid >> 1][tid & 1] = 0u; }
        __syncthreads();
        #pragma unroll
        for (int r = 0; r < 4; ++r) {
            #pragma unroll
            for (int c = 0; c < 4; ++c) {
                int li = ty + 16 * r, lj = tx + 16 * c;
                int gi = ti * TS + li, gj = tj * TS + lj;
                bool bit = false;
                if (gi < gj) {
                    float ep = 1.0f / (1.0f + expf(-acc[r][c]));
                    float P = ep / epmax;
                    float Pc = fminf(fmaxf(P, 1e-6f), 1.0f - 1e-6f);
                    float uu = u[(size_t)gi * NN + gj];
                    float ucv = fminf(fmaxf(uu, 1e-6f), 1.0f - 1e-6f);
                    bit = Pc > (1.0f - ucv);
                } else if (gi == gj) {
                    bit = true;
                }
                if (bit) {
                    atomicOr(&lm[li][lj >> 5], 1u << (lj & 31));
                    atomicOr(&lmT[lj][li >> 5], 1u << (li & 31));
                }
            }
        }
        __syncthreads();
        if (tid < 128) {
            int r = tid >> 1, wq = tid & 1;
            unsigned word = lm[r][wq];
            if (ti == tj) word |= lmT[r][wq];
            mb[(size_t)(ti * TS + r) * 128 + tj * 2 + wq] = word;
        } else if (ti != tj) {
            int r = (tid - 128) >> 1, wq = tid & 1;
            mb[(size_t)(tj * TS + r) * 128 + ti * 2 + wq] = lmT[r][wq];
        }
    }
}

// Pass 1 (S-store path): compute tile, store S to ws, fold into global max.
__global__ __launch_bounds__(256, 4) void k_stile_store(const float* __restrict__ h,
                                                        float* __restrict__ S,
                                                        unsigned* __restrict__ smax_key) {
    int ti = blockIdx.y, tj = blockIdx.x;
    if (tj < ti) return;
    __shared__ float Ah[TS][68];
    __shared__ float Bh[TS][68];
    int tid = threadIdx.x;
    int tx = tid & 15, ty = tid >> 4;
    const float* ha = h + (size_t)ti * TS * 128;
    const float* hb = h + (size_t)tj * TS * 128;

    float acc[4][4];
    #pragma unroll
    for (int r = 0; r < 4; ++r)
        #pragma unroll
        for (int c = 0; c < 4; ++c) acc[r][c] = 0.0f;

    for (int half = 0; half < 2; ++half) {
        __syncthreads();
        #pragma unroll
        for (int t = 0; t < 4; ++t) {
            int f = tid + t * 256;
            int row = f >> 4, kk = f & 15;
            *(float4*)&Ah[row][kk * 4] = *(const float4*)(ha + (size_t)row * 128 + half * 64 + kk * 4);
            *(float4*)&Bh[row][kk * 4] = *(const float4*)(hb + (size_t)row * 128 + half * 64 + kk * 4);
        }
        __syncthreads();
        #pragma unroll 2
        for (int k4 = 0; k4 < 16; ++k4) {
            float4 a[4], b[4];
            #pragma unroll
            for (int r = 0; r < 4; ++r) a[r] = *(const float4*)&Ah[ty + 16 * r][k4 * 4];
            #pragma unroll
            for (int c = 0; c < 4; ++c) b[c] = *(const float4*)&Bh[tx + 16 * c][k4 * 4];
            #pragma unroll
            for (int r = 0; r < 4; ++r)
                #pragma unroll
                for (int c = 0; c < 4; ++c) {
                    acc[r][c] = fmaf(a[r].x, b[c].x, acc[r][c]);
                    acc[r][c] = fmaf(a[r].y, b[c].y, acc[r][c]);
                    acc[r][c] = fmaf(a[r].z, b[c].z, acc[r][c]);
                    acc[r][c] = fmaf(a[r].w, b[c].w, acc[r][c]);
                }
        }
    }

    float* sp = S + (size_t)(ti * 64 + tj) * 4096;
    #pragma unroll
    for (int r = 0; r < 4; ++r)
        #pragma unroll
        for (int c = 0; c < 4; ++c)
            sp[(ty + 16 * r) * 64 + tx + 16 * c] = acc[r][c];

    float m = -3.4e38f;
    #pragma unroll
    for (int r = 0; r < 4; ++r)
        #pragma unroll
        for (int c = 0; c < 4; ++c) m = fmaxf(m, acc[r][c]);
    #pragma unroll
    for (int o = 1; o < 64; o <<= 1) m = fmaxf(m, __shfl_xor(m, o, 64));
    __shared__ float wm[4];
    if ((tid & 63) == 0) wm[tid >> 6] = m;
    __syncthreads();
    if (tid == 0)
        atomicMax(smax_key, fkey(fmaxf(fmaxf(wm[0], wm[1]), fmaxf(wm[2], wm[3]))));
}

// Pass 2 (S-store path): read stored S, emit mask bits.
__global__ __launch_bounds__(256, 4) void k_bitemit(const float* __restrict__ S,
                                                    const float* __restrict__ u,
                                                    const unsigned* __restrict__ smax_key,
                                                    unsigned* __restrict__ mb) {
    int ti = blockIdx.y, tj = blockIdx.x;
    if (tj < ti) return;
    int tid = threadIdx.x;
    int tx = tid & 15, ty = tid >> 4;
    float smax = funkey(*smax_key);
    float epmax = 1.0f / (1.0f + expf(-smax));
    __shared__ unsigned lm[TS][2];
    __shared__ unsigned lmT[TS][2];
    if (tid < 128) { lm[tid >> 1][tid & 1] = 0u; lmT[tid >> 1][tid & 1] = 0u; }
    __syncthreads();
    const float* sp = S + (size_t)(ti * 64 + tj) * 4096;
    #pragma unroll
    for (int r = 0; r < 4; ++r) {
        #pragma unroll
        for (int c = 0; c < 4; ++c) {
            int li = ty + 16 * r, lj = tx + 16 * c;
            int gi = ti * TS + li, gj = tj * TS + lj;
            bool bit = false;
            if (gi < gj) {
                float ep = 1.0f / (1.0f + expf(-sp[li * 64 + lj]));
                float P = ep / epmax;
                float Pc = fminf(fmaxf(P, 1e-6f), 1.0f - 1e-6f);
                float uu = u[(size_t)gi * NN + gj];
                float ucv = fminf(fmaxf(uu, 1e-6f), 1.0f - 1e-6f);
                bit = Pc > (1.0f - ucv);
            } else if (gi == gj) {
                bit = true;
            }
            if (bit) {
                atomicOr(&lm[li][lj >> 5], 1u << (lj & 31));
                atomicOr(&lmT[lj][li >> 5], 1u << (li & 31));
            }
        }
    }
    __syncthreads();
    if (tid < 128) {
        int r = tid >> 1, wq = tid & 1;
        unsigned word = lm[r][wq];
        if (ti == tj) word |= lmT[r][wq];
        mb[(size_t)(ti * TS + r) * 128 + tj * 2 + wq] = word;
    } else if (ti != tj) {
        int r = (tid - 128) >> 1, wq = tid & 1;
        mb[(size_t)(tj * TS + r) * 128 + ti * 2 + wq] = lmT[r][wq];
    }
}

// Masked max, D=256. RT=16/JS=8 -> 2048 blocks (8/CU). Wave-uniform mask in
// SGPR (readfirstlane); sext in C++ (SALU); asm-pinned v_and(s,v) + v_max3.
template<int RT, int JS>
__global__ __launch_bounds__(256, 8) void k_mmax256(const unsigned* __restrict__ mb,
                                                    const float* __restrict__ z,
                                                    float* __restrict__ part) {
    constexpr int JPS = NN / JS;   // 512
    constexpr int WPS = JPS / 32;  // 16
    constexpr int RPG = RT / 4;    // 4
    constexpr int NRB = NN / RT;   // 256
    int rowblk = blockIdx.x % NRB, js = blockIdx.x / NRB;
    int i0 = rowblk * RT;

    __shared__ unsigned msk[RT][WPS + 1];
    {
        int t = threadIdx.x;           // RT*WPS == 256
        msk[t / WPS][t % WPS] = mb[(size_t)(i0 + t / WPS) * 128 + js * WPS + t % WPS];
    }
    __syncthreads();

    int d4 = threadIdx.x & 63;
    int g = threadIdx.x >> 6;
    const float4* zbase = (const float4*)z + (size_t)js * JPS * 64 + d4;

    float4 acc[RPG];
    #pragma unroll
    for (int r = 0; r < RPG; ++r) acc[r] = make_float4(0.f, 0.f, 0.f, 0.f);

    #pragma unroll 1
    for (int wq = 0; wq < WPS; ++wq) {
        unsigned m[RPG];
        #pragma unroll
        for (int r = 0; r < RPG; ++r)
            m[r] = (unsigned)__builtin_amdgcn_readfirstlane((int)msk[g * RPG + r][wq]);
        const float4* zp = zbase + (size_t)(wq * 32) * 64;
        #pragma unroll 2
        for (int j4 = 0; j4 < 32; j4 += 4) {
            float4 z0 = zp[0 * 64];
            float4 z1 = zp[1 * 64];
            float4 z2 = zp[2 * 64];
            float4 z3 = zp[3 * 64];
            #pragma unroll
            for (int r = 0; r < RPG; ++r) {
                unsigned s0 = bit_sext_s(m[r], j4 + 0);
                unsigned s1 = bit_sext_s(m[r], j4 + 1);
                unsigned s2 = bit_sext_s(m[r], j4 + 2);
                unsigned s3 = bit_sext_s(m[r], j4 + 3);
                max3v(acc[r], andv_s(s0, z0), andv_s(s1, z1));
                max3v(acc[r], andv_s(s2, z2), andv_s(s3, z3));
            }
            zp += 4 * 64;
        }
    }

    float4* po = (float4*)(part + (size_t)js * NN * 256);
    #pragma unroll
    for (int r = 0; r < RPG; ++r)
        po[(size_t)(i0 + g * RPG + r) * 64 + d4] = acc[r];
}

// Masked max, D=128. Wave covers 2 j's (jpar = lane>>5); mask word in SGPR,
// per-lane bit offset extracted via asm v_bfe_i32; asm v_and + v_max3.
template<int RT, int JS>
__global__ __launch_bounds__(256, 8) void k_mmax128(const unsigned* __restrict__ mb,
                                                    const float* __restrict__ z,
                                                    float* __restrict__ part) {
    constexpr int JPS = NN / JS;   // 512
    constexpr int WPS = JPS / 32;  // 16
    constexpr int RPG = RT / 4;    // 4
    constexpr int NRB = NN / RT;   // 256
    int rowblk = blockIdx.x % NRB, js = blockIdx.x / NRB;
    int i0 = rowblk * RT;

    __shared__ unsigned msk[RT][WPS + 1];
    {
        int t = threadIdx.x;
        msk[t / WPS][t % WPS] = mb[(size_t)(i0 + t / WPS) * 128 + js * WPS + t % WPS];
    }
    __syncthreads();

    int lane = threadIdx.x & 63;
    int g = threadIdx.x >> 6;
    unsigned jpar = lane >> 5;
    int d4 = lane & 31;
    const float4* zbase = (const float4*)z + (size_t)js * JPS * 32 + d4;

    float4 acc[RPG];
    #pragma unroll
    for (int r = 0; r < RPG; ++r) acc[r] = make_float4(0.f, 0.f, 0.f, 0.f);

    #pragma unroll 1
    for (int wq = 0; wq < WPS; ++wq) {
        unsigned m[RPG];
        #pragma unroll
        for (int r = 0; r < RPG; ++r)
            m[r] = (unsigned)__builtin_amdgcn_readfirstlane((int)msk[g * RPG + r][wq]);
        const float4* zp = zbase + (size_t)(wq * 32) * 32;
        #pragma unroll 2
        for (int j4 = 0; j4 < 32; j4 += 4) {
            float4 za = zp[(size_t)jpar * 32];
            float4 zb = zp[(size_t)(2 + jpar) * 32];
            unsigned oa = j4 + jpar, ob = j4 + 2 + jpar;
            #pragma unroll
            for (int r = 0; r < RPG; ++r) {
                unsigned sa = vbfe1(m[r], oa);
                unsigned sb = vbfe1(m[r], ob);
                max3v(acc[r], andv_v(sa, za), andv_v(sb, zb));
            }
            zp += 4 * 32;
        }
    }

    #pragma unroll
    for (int r = 0; r < RPG; ++r) {
        acc[r].x = fmaxf(acc[r].x, __shfl_xor(acc[r].x, 32, 64));
        acc[r].y = fmaxf(acc[r].y, __shfl_xor(acc[r].y, 32, 64));
        acc[r].z = fmaxf(acc[r].z, __shfl_xor(acc[r].z, 32, 64));
        acc[r].w = fmaxf(acc[r].w, __shfl_xor(acc[r].w, 32, 64));
    }
    if (!jpar) {
        float4* po = (float4*)(part + (size_t)js * NN * 128);
        #pragma unroll
        for (int r = 0; r < RPG; ++r)
            po[(size_t)(i0 + g * RPG + r) * 32 + d4] = acc[r];
    }
}

__global__ void k_relu_l2norm(float* __restrict__ h) {
    int i = blockIdx.x, d = threadIdx.x;
    float v = fmaxf(h[(size_t)i * 128 + d], 0.0f);
    float ss = v * v;
    #pragma unroll
    for (int o = 1; o < 64; o <<= 1) ss += __shfl_xor(ss, o, 64);
    __shared__ float w2[2];
    if ((d & 63) == 0) w2[d >> 6] = ss;
    __syncthreads();
    float tot = w2[0] + w2[1];
    float denom = fmaxf(sqrtf(tot), 1e-12f);
    h[(size_t)i * 128 + d] = v / denom;
}

// Final 128->32 GEMM with NS-way partial merge, LDS-staged. 4 rows per block.
template<int NS>
__global__ void k_gemm_final(const float* __restrict__ X, size_t xstride,
                             const float* __restrict__ W,
                             const float* __restrict__ b1, const float* __restrict__ b2,
                             float* __restrict__ out) {
    __shared__ float xr[4][128];
    int i0 = blockIdx.x * 4;
    for (int t = threadIdx.x; t < 512; t += 128) {
        int r = t >> 7, k = t & 127;
        float v = X[(size_t)(i0 + r) * 128 + k];
        #pragma unroll
        for (int s = 1; s < NS; ++s)
            v = fmaxf(v, X[(size_t)s * xstride + (size_t)(i0 + r) * 128 + k]);
        xr[r][k] = v;
    }
    __syncthreads();
    int il = threadIdx.x >> 5, j = threadIdx.x & 31;
    float acc = 0.0f;
    #pragma unroll 8
    for (int k = 0; k < 128; ++k) acc = fmaf(xr[il][k], W[k * 32 + j], acc);
    out[(size_t)(i0 + il) * 32 + j] = acc + b1[j] + b2[j];
}

extern "C" void kernel_launch(void* const* d_in, const int* in_sizes, int n_in,
                              void* d_out, int out_size, void* d_ws, size_t ws_size,
                              hipStream_t stream) {
    const float* inputs = (const float*)d_in[1];
    const float* feat   = (const float*)d_in[2];
    const float* u      = (const float*)d_in[3];
    const int*   src    = (const int*)d_in[4];
    const int*   dst    = (const int*)d_in[5];
    const float* gc0W = (const float*)d_in[6],  *gc0b = (const float*)d_in[7];
    const float* gc1W = (const float*)d_in[8],  *gc1b = (const float*)d_in[9];
    const float* p0W  = (const float*)d_in[10], *p0b  = (const float*)d_in[11];
    const float* l0W  = (const float*)d_in[12], *l0b  = (const float*)d_in[13];
    const float* b0   = (const float*)d_in[14];
    const float* p1W  = (const float*)d_in[15], *p1b  = (const float*)d_in[16];
    const float* l1W  = (const float*)d_in[17], *l1b  = (const float*)d_in[18];
    const float* b1   = (const float*)d_in[19];
    const float* p2W  = (const float*)d_in[20], *p2b  = (const float*)d_in[21];
    const float* l2W  = (const float*)d_in[22], *l2b  = (const float*)d_in[23];
    const float* b2   = (const float*)d_in[24];
    float* out = (float*)d_out;

    const size_t MB = 1048576;
    char* w = (char*)d_ws;
    int*      cnt_src  = (int*)(w + 0);            // 16 KB
    int*      cnt_dst  = (int*)(w + 16384);        // 16 KB
    float*    on       = (float*)(w + 32768);      // 16 KB
    float*    inn      = (float*)(w + 49152);      // 16 KB
    unsigned* smax_key = (unsigned*)(w + 65536);   // pad to 128 KB
    char*     big      = w + 131072;
    float*    tmp      = (float*)(big);            // 2 MB
    float*    agg      = (float*)(big + 2 * MB);   // 2 MB
    float*    hbuf     = (float*)(big + 4 * MB);   // 2 MB
    unsigned* mb       = (unsigned*)(big + 6 * MB);// 2 MB
    float*    z        = (float*)(big + 8 * MB);   // 4 MB
    float*    pm       = (float*)(big + 12 * MB);  // 32 MB (8 split partials)
    float*    hs       = (float*)(big + 44 * MB);  // 2 MB
    float*    Sbuf     = (float*)(big + 46 * MB);  // 64 MB
    bool use_sstore = ws_size >= 131072 + 110 * MB;

    hipMemsetAsync(w, 0, 131072, stream);
    k_count<<<EE / 256, 256, 0, stream>>>(src, dst, cnt_src, cnt_dst);
    k_norm<<<NN / 256, 256, 0, stream>>>(cnt_src, cnt_dst, on, inn);

    // --- GCN layer 0 ---
    k_gemm_scale<256, 128, 4><<<NN / 4, 128, 0, stream>>>(inputs, gc0W, on, tmp);
    hipMemsetAsync(agg, 0, (size_t)NN * 128 * 4, stream);
    k_scatter<<<EE, 128, 0, stream>>>(tmp, src, dst, agg);
    k_gcn_out<<<NN * 128 / 256, 256, 0, stream>>>(agg, inn, gc0b, hbuf, 1);

    // --- GCN layer 1 ---
    k_gemm_scale<128, 128, 4><<<NN / 4, 128, 0, stream>>>(hbuf, gc1W, on, tmp);
    hipMemsetAsync(agg, 0, (size_t)NN * 128 * 4, stream);
    k_scatter<<<EE, 128, 0, stream>>>(tmp, src, dst, agg);
    k_gcn_out<<<NN * 128 / 256, 256, 0, stream>>>(agg, inn, gc1b, hbuf, 0);

    // --- decode: S max + mask bits ---
    dim3 tg(64, 64);
    if (use_sstore) {
        k_stile_store<<<tg, 256, 0, stream>>>(hbuf, Sbuf, smax_key);
        k_bitemit<<<tg, 256, 0, stream>>>(Sbuf, u, smax_key, mb);
    } else {
        k_stile<0><<<tg, 256, 0, stream>>>(hbuf, nullptr, smax_key, nullptr);
        k_stile<1><<<tg, 256, 0, stream>>>(hbuf, u, smax_key, mb);
    }

    // --- GraphSAGE layer 0 (256 -> 128) ---
    k_gemm_mrg<256, 256, 1, 4><<<NN / 4, 256, 0, stream>>>(feat, 0, p0W, p0b, nullptr, z, 1);
    k_mmax256<16, 8><<<(NN / 16) * 8, 256, 0, stream>>>(mb, z, pm);
    k_gemm_mrg<256, 128, 8, 4><<<NN / 4, 128, 0, stream>>>(pm, (size_t)NN * 256, l0W, l0b, b0, hs, 0);
    k_relu_l2norm<<<NN, 128, 0, stream>>>(hs);

    // --- GraphSAGE layer 1 (128 -> 128) ---
    k_gemm_mrg<128, 128, 1, 4><<<NN / 4, 128, 0, stream>>>(hs, 0, p1W, p1b, nullptr, z, 1);
    k_mmax128<16, 8><<<(NN / 16) * 8, 256, 0, stream>>>(mb, z, pm);
    k_gemm_mrg<128, 128, 8, 4><<<NN / 4, 128, 0, stream>>>(pm, (size_t)NN * 128, l1W, l1b, b1, tmp, 0);
    k_relu_l2norm<<<NN, 128, 0, stream>>>(tmp);

    // --- GraphSAGE layer 2 (128 -> 32) ---
    k_gemm_mrg<128, 128, 1, 4><<<NN / 4, 128, 0, stream>>>(tmp, 0, p2W, p2b, nullptr, z, 1);
    k_mmax128<16, 8><<<(NN / 16) * 8, 256, 0, stream>>>(mb, z, pm);
    k_gemm_final<8><<<NN / 4, 128, 0, stream>>>(pm, (size_t)NN * 128, l2W, l2b, b2, out);
}

// Round 15
// 711.882 us; speedup vs baseline: 1.2571x; 1.0637x over previous
//
#include <hip/hip_runtime.h>
#include <hip/hip_fp16.h>
#include <cstdint>
#include <cstddef>

#define NN 4096
#define EE 131072
#define TS 64

__device__ __forceinline__ unsigned fkey(float f) {
    unsigned u = __float_as_uint(f);
    return (u & 0x80000000u) ? ~u : (u | 0x80000000u);
}
__device__ __forceinline__ float funkey(unsigned k) {
    unsigned u = (k & 0x80000000u) ? (k & 0x7fffffffu) : ~k;
    return __uint_as_float(u);
}

// ---- VALU-only asm pins (no SALU/SCC writes; proven safe round 14) ----
__device__ __forceinline__ void max3v(float4& a, float4 b, float4 c) {
    asm("v_max3_f32 %0, %0, %1, %2" : "+v"(a.x) : "v"(b.x), "v"(c.x));
    asm("v_max3_f32 %0, %0, %1, %2" : "+v"(a.y) : "v"(b.y), "v"(c.y));
    asm("v_max3_f32 %0, %0, %1, %2" : "+v"(a.z) : "v"(b.z), "v"(c.z));
    asm("v_max3_f32 %0, %0, %1, %2" : "+v"(a.w) : "v"(b.w), "v"(c.w));
}
__device__ __forceinline__ float4 andv_v(unsigned vm, float4 v) {
    float4 o;
    asm("v_and_b32 %0, %1, %2" : "=v"(o.x) : "v"(vm), "v"(v.x));
    asm("v_and_b32 %0, %1, %2" : "=v"(o.y) : "v"(vm), "v"(v.y));
    asm("v_and_b32 %0, %1, %2" : "=v"(o.z) : "v"(vm), "v"(v.z));
    asm("v_and_b32 %0, %1, %2" : "=v"(o.w) : "v"(vm), "v"(v.w));
    return o;
}
__device__ __forceinline__ unsigned vbfe1(unsigned m, unsigned off) {
    unsigned t;
    asm("v_bfe_i32 %0, %1, %2, 1" : "=v"(t) : "s"(m), "v"(off));
    return t;
}
// packed-half max: a = pk_max(a, x)
__device__ __forceinline__ void pkmax(unsigned& a, unsigned x) {
    asm("v_pk_max_f16 %0, %0, %1" : "+v"(a) : "v"(x));
}
// scalar-friendly sext-bit (compiler emits SALU for wave-uniform input)
__device__ __forceinline__ unsigned bit_sext_s(unsigned w, int off) {
    return (unsigned)(((int)(w << (31 - off))) >> 31);
}

__global__ void k_count(const int* __restrict__ src, const int* __restrict__ dst,
                        int* __restrict__ cs, int* __restrict__ cd) {
    int e = blockIdx.x * 256 + threadIdx.x;
    if (e < EE) {
        atomicAdd(&cs[src[e]], 1);
        atomicAdd(&cd[dst[e]], 1);
    }
}

__global__ void k_norm(const int* __restrict__ cs, const int* __restrict__ cd,
                       float* __restrict__ on, float* __restrict__ inn) {
    int i = blockIdx.x * 256 + threadIdx.x;
    if (i < NN) {
        int a = cs[i] > 1 ? cs[i] : 1;
        int b = cd[i] > 1 ? cd[i] : 1;
        on[i]  = 1.0f / sqrtf((float)a);
        inn[i] = 1.0f / sqrtf((float)b);
    }
}

// RB rows per block: W[k][j] read once per block for RB rows.
template<int K, int ND, int RB>
__global__ void k_gemm_scale(const float* __restrict__ X, const float* __restrict__ W,
                             const float* __restrict__ scale, float* __restrict__ out) {
    __shared__ float xr[RB][K];
    int i0 = blockIdx.x * RB;
    for (int t = threadIdx.x; t < RB * K; t += ND)
        xr[t / K][t % K] = X[(size_t)(i0 + t / K) * K + t % K];
    __syncthreads();
    int j = threadIdx.x;
    float acc[RB];
    #pragma unroll
    for (int r = 0; r < RB; ++r) acc[r] = 0.0f;
    #pragma unroll 4
    for (int k = 0; k < K; ++k) {
        float w = W[k * ND + j];
        #pragma unroll
        for (int r = 0; r < RB; ++r) acc[r] = fmaf(xr[r][k], w, acc[r]);
    }
    #pragma unroll
    for (int r = 0; r < RB; ++r)
        out[(size_t)(i0 + r) * ND + j] = acc[r] * scale[i0 + r];
}

// out = (max over NS split-partials of X) @ W + b1 (+b2), RB rows/block.
// L2N=1: fused relu + row l2-normalize epilogue (same reduction order as the
// standalone k_relu_l2norm: shfl width-64 then 2-way LDS sum).
template<int K, int ND, int NS, int RB, int L2N>
__global__ void k_gemm_mrg(const float* __restrict__ X, size_t xstride,
                           const float* __restrict__ W,
                           const float* __restrict__ b1, const float* __restrict__ b2,
                           float* __restrict__ out, int do_relu) {
    __shared__ float xr[RB][K];
    int i0 = blockIdx.x * RB;
    for (int t = threadIdx.x; t < RB * K; t += ND) {
        size_t off = (size_t)(i0 + t / K) * K + t % K;
        float v = X[off];
        #pragma unroll
        for (int s = 1; s < NS; ++s) v = fmaxf(v, X[(size_t)s * xstride + off]);
        xr[t / K][t % K] = v;
    }
    __syncthreads();
    int j = threadIdx.x;
    float acc[RB];
    #pragma unroll
    for (int r = 0; r < RB; ++r) acc[r] = 0.0f;
    #pragma unroll 4
    for (int k = 0; k < K; ++k) {
        float w = W[k * ND + j];
        #pragma unroll
        for (int r = 0; r < RB; ++r) acc[r] = fmaf(xr[r][k], w, acc[r]);
    }
    if constexpr (L2N) {
        float v[RB], ss[RB];
        #pragma unroll
        for (int r = 0; r < RB; ++r) {
            float t = acc[r] + b1[j];
            if (b2) t += b2[j];
            v[r] = fmaxf(t, 0.0f);
            ss[r] = v[r] * v[r];
        }
        #pragma unroll
        for (int o = 1; o < 64; o <<= 1)
            #pragma unroll
            for (int r = 0; r < RB; ++r) ss[r] += __shfl_xor(ss[r], o, 64);
        __shared__ float sred[RB][2];
        if ((threadIdx.x & 63) == 0)
            #pragma unroll
            for (int r = 0; r < RB; ++r) sred[r][threadIdx.x >> 6] = ss[r];
        __syncthreads();
        #pragma unroll
        for (int r = 0; r < RB; ++r) {
            float tot = sred[r][0] + sred[r][1];
            out[(size_t)(i0 + r) * ND + j] = v[r] / fmaxf(sqrtf(tot), 1e-12f);
        }
    } else {
        #pragma unroll
        for (int r = 0; r < RB; ++r) {
            float v = acc[r] + b1[j];
            if (b2) v += b2[j];
            if (do_relu) v = fmaxf(v, 0.0f);
            out[(size_t)(i0 + r) * ND + j] = v;
        }
    }
}

__global__ void k_scatter(const float* __restrict__ t, const int* __restrict__ src,
                          const int* __restrict__ dst, float* __restrict__ agg) {
    int e = blockIdx.x;
    int j = threadIdx.x;   // 128 threads
    int s = src[e], d = dst[e];
    atomicAdd(&agg[(size_t)d * 128 + j], t[(size_t)s * 128 + j]);
}

__global__ void k_gcn_out(const float* __restrict__ agg, const float* __restrict__ inn,
                          const float* __restrict__ b, float* __restrict__ out, int do_relu) {
    int idx = blockIdx.x * 256 + threadIdx.x;
    int i = idx >> 7, j = idx & 127;
    float v = agg[idx] * inn[i] + b[j];
    if (do_relu) v = fmaxf(v, 0.0f);
    out[idx] = v;
}

// ---- S = h h^T 64x64 tile; MODE 0: max-only; MODE 1: recompute + bit-emit ----
template<int MODE>
__global__ __launch_bounds__(256, 4) void k_stile(const float* __restrict__ h,
                                                  const float* __restrict__ u,
                                                  unsigned* __restrict__ smax_key,
                                                  unsigned* __restrict__ mb) {
    int ti = blockIdx.y, tj = blockIdx.x;
    if (tj < ti) return;
    __shared__ float Ah[TS][68];
    __shared__ float Bh[TS][68];
    int tid = threadIdx.x;
    int tx = tid & 15, ty = tid >> 4;
    const float* ha = h + (size_t)ti * TS * 128;
    const float* hb = h + (size_t)tj * TS * 128;

    float acc[4][4];
    #pragma unroll
    for (int r = 0; r < 4; ++r)
        #pragma unroll
        for (int c = 0; c < 4; ++c) acc[r][c] = 0.0f;

    for (int half = 0; half < 2; ++half) {
        __syncthreads();
        #pragma unroll
        for (int t = 0; t < 4; ++t) {
            int f = tid + t * 256;
            int row = f >> 4, kk = f & 15;
            *(float4*)&Ah[row][kk * 4] = *(const float4*)(ha + (size_t)row * 128 + half * 64 + kk * 4);
            *(float4*)&Bh[row][kk * 4] = *(const float4*)(hb + (size_t)row * 128 + half * 64 + kk * 4);
        }
        __syncthreads();
        #pragma unroll 2
        for (int k4 = 0; k4 < 16; ++k4) {
            float4 a[4], b[4];
            #pragma unroll
            for (int r = 0; r < 4; ++r) a[r] = *(const float4*)&Ah[ty + 16 * r][k4 * 4];
            #pragma unroll
            for (int c = 0; c < 4; ++c) b[c] = *(const float4*)&Bh[tx + 16 * c][k4 * 4];
            #pragma unroll
            for (int r = 0; r < 4; ++r)
                #pragma unroll
                for (int c = 0; c < 4; ++c) {
                    acc[r][c] = fmaf(a[r].x, b[c].x, acc[r][c]);
                    acc[r][c] = fmaf(a[r].y, b[c].y, acc[r][c]);
                    acc[r][c] = fmaf(a[r].z, b[c].z, acc[r][c]);
                    acc[r][c] = fmaf(a[r].w, b[c].w, acc[r][c]);
                }
        }
    }

    if constexpr (MODE == 0) {
        float m = -3.4e38f;
        #pragma unroll
        for (int r = 0; r < 4; ++r)
            #pragma unroll
            for (int c = 0; c < 4; ++c) m = fmaxf(m, acc[r][c]);
        #pragma unroll
        for (int o = 1; o < 64; o <<= 1) m = fmaxf(m, __shfl_xor(m, o, 64));
        __shared__ float wm[4];
        if ((tid & 63) == 0) wm[tid >> 6] = m;
        __syncthreads();
        if (tid == 0) {
            float mm = fmaxf(fmaxf(wm[0], wm[1]), fmaxf(wm[2], wm[3]));
            atomicMax(smax_key, fkey(mm));
        }
    } else {
        float smax = funkey(*smax_key);
        float epmax = 1.0f / (1.0f + expf(-smax));
        __shared__ unsigned lm[TS][2];
        __shared__ unsigned lmT[TS][2];
        if (tid < 128) { lm[tid >> 1][tid & 1] = 0u; lmT[tid >> 1][tid & 1] = 0u; }
        __syncthreads();
        #pragma unroll
        for (int r = 0; r < 4; ++r) {
            #pragma unroll
            for (int c = 0; c < 4; ++c) {
                int li = ty + 16 * r, lj = tx + 16 * c;
                int gi = ti * TS + li, gj = tj * TS + lj;
                bool bit = false;
                if (gi < gj) {
                    float ep = 1.0f / (1.0f + expf(-acc[r][c]));
                    float P = ep / epmax;
                    float Pc = fminf(fmaxf(P, 1e-6f), 1.0f - 1e-6f);
                    float uu = u[(size_t)gi * NN + gj];
                    float ucv = fminf(fmaxf(uu, 1e-6f), 1.0f - 1e-6f);
                    bit = Pc > (1.0f - ucv);
                } else if (gi == gj) {
                    bit = true;
                }
                if (bit) {
                    atomicOr(&lm[li][lj >> 5], 1u << (lj & 31));
                    atomicOr(&lmT[lj][li >> 5], 1u << (li & 31));
                }
            }
        }
        __syncthreads();
        if (tid < 128) {
            int r = tid >> 1, wq = tid & 1;
            unsigned word = lm[r][wq];
            if (ti == tj) word |= lmT[r][wq];
            mb[(size_t)(ti * TS + r) * 128 + tj * 2 + wq] = word;
        } else if (ti != tj) {
            int r = (tid - 128) >> 1, wq = tid & 1;
            mb[(size_t)(tj * TS + r) * 128 + ti * 2 + wq] = lmT[r][wq];
        }
    }
}

// Pass 1 (S-store path): compute tile, store S to ws, fold into global max.
__global__ __launch_bounds__(256, 4) void k_stile_store(const float* __restrict__ h,
                                                        float* __restrict__ S,
                                                        unsigned* __restrict__ smax_key) {
    int ti = blockIdx.y, tj = blockIdx.x;
    if (tj < ti) return;
    __shared__ float Ah[TS][68];
    __shared__ float Bh[TS][68];
    int tid = threadIdx.x;
    int tx = tid & 15, ty = tid >> 4;
    const float* ha = h + (size_t)ti * TS * 128;
    const float* hb = h + (size_t)tj * TS * 128;

    float acc[4][4];
    #pragma unroll
    for (int r = 0; r < 4; ++r)
        #pragma unroll
        for (int c = 0; c < 4; ++c) acc[r][c] = 0.0f;

    for (int half = 0; half < 2; ++half) {
        __syncthreads();
        #pragma unroll
        for (int t = 0; t < 4; ++t) {
            int f = tid + t * 256;
            int row = f >> 4, kk = f & 15;
            *(float4*)&Ah[row][kk * 4] = *(const float4*)(ha + (size_t)row * 128 + half * 64 + kk * 4);
            *(float4*)&Bh[row][kk * 4] = *(const float4*)(hb + (size_t)row * 128 + half * 64 + kk * 4);
        }
        __syncthreads();
        #pragma unroll 2
        for (int k4 = 0; k4 < 16; ++k4) {
            float4 a[4], b[4];
            #pragma unroll
            for (int r = 0; r < 4; ++r) a[r] = *(const float4*)&Ah[ty + 16 * r][k4 * 4];
            #pragma unroll
            for (int c = 0; c < 4; ++c) b[c] = *(const float4*)&Bh[tx + 16 * c][k4 * 4];
            #pragma unroll
            for (int r = 0; r < 4; ++r)
                #pragma unroll
                for (int c = 0; c < 4; ++c) {
                    acc[r][c] = fmaf(a[r].x, b[c].x, acc[r][c]);
                    acc[r][c] = fmaf(a[r].y, b[c].y, acc[r][c]);
                    acc[r][c] = fmaf(a[r].z, b[c].z, acc[r][c]);
                    acc[r][c] = fmaf(a[r].w, b[c].w, acc[r][c]);
                }
        }
    }

    float* sp = S + (size_t)(ti * 64 + tj) * 4096;
    #pragma unroll
    for (int r = 0; r < 4; ++r)
        #pragma unroll
        for (int c = 0; c < 4; ++c)
            sp[(ty + 16 * r) * 64 + tx + 16 * c] = acc[r][c];

    float m = -3.4e38f;
    #pragma unroll
    for (int r = 0; r < 4; ++r)
        #pragma unroll
        for (int c = 0; c < 4; ++c) m = fmaxf(m, acc[r][c]);
    #pragma unroll
    for (int o = 1; o < 64; o <<= 1) m = fmaxf(m, __shfl_xor(m, o, 64));
    __shared__ float wm[4];
    if ((tid & 63) == 0) wm[tid >> 6] = m;
    __syncthreads();
    if (tid == 0)
        atomicMax(smax_key, fkey(fmaxf(fmaxf(wm[0], wm[1]), fmaxf(wm[2], wm[3]))));
}

// Pass 2 (S-store path): read stored S, emit mask bits.
__global__ __launch_bounds__(256, 4) void k_bitemit(const float* __restrict__ S,
                                                    const float* __restrict__ u,
                                                    const unsigned* __restrict__ smax_key,
                                                    unsigned* __restrict__ mb) {
    int ti = blockIdx.y, tj = blockIdx.x;
    if (tj < ti) return;
    int tid = threadIdx.x;
    int tx = tid & 15, ty = tid >> 4;
    float smax = funkey(*smax_key);
    float epmax = 1.0f / (1.0f + expf(-smax));
    __shared__ unsigned lm[TS][2];
    __shared__ unsigned lmT[TS][2];
    if (tid < 128) { lm[tid >> 1][tid & 1] = 0u; lmT[tid >> 1][tid & 1] = 0u; }
    __syncthreads();
    const float* sp = S + (size_t)(ti * 64 + tj) * 4096;
    #pragma unroll
    for (int r = 0; r < 4; ++r) {
        #pragma unroll
        for (int c = 0; c < 4; ++c) {
            int li = ty + 16 * r, lj = tx + 16 * c;
            int gi = ti * TS + li, gj = tj * TS + lj;
            bool bit = false;
            if (gi < gj) {
                float ep = 1.0f / (1.0f + expf(-sp[li * 64 + lj]));
                float P = ep / epmax;
                float Pc = fminf(fmaxf(P, 1e-6f), 1.0f - 1e-6f);
                float uu = u[(size_t)gi * NN + gj];
                float ucv = fminf(fmaxf(uu, 1e-6f), 1.0f - 1e-6f);
                bit = Pc > (1.0f - ucv);
            } else if (gi == gj) {
                bit = true;
            }
            if (bit) {
                atomicOr(&lm[li][lj >> 5], 1u << (lj & 31));
                atomicOr(&lmT[lj][li >> 5], 1u << (li & 31));
            }
        }
    }
    __syncthreads();
    if (tid < 128) {
        int r = tid >> 1, wq = tid & 1;
        unsigned word = lm[r][wq];
        if (ti == tj) word |= lmT[r][wq];
        mb[(size_t)(ti * TS + r) * 128 + tj * 2 + wq] = word;
    } else if (ti != tj) {
        int r = (tid - 128) >> 1, wq = tid & 1;
        mb[(size_t)(tj * TS + r) * 128 + ti * 2 + wq] = lmT[r][wq];
    }
}

// Convert f32 z (NN x 256) to packed half2 (NN x 128 u32).
__global__ void k_f2h(const float* __restrict__ z, unsigned* __restrict__ zh) {
    int idx = blockIdx.x * 256 + threadIdx.x;   // NN*128 total
    float2 v = *(const float2*)(z + (size_t)idx * 2);
    __half2 h = __floats2half2_rn(v.x, v.y);
    zh[idx] = *(unsigned*)&h;
}

// Masked max, D=256, fp16-packed z. Lane d covers halves [4d,4d+4) as uint2.
// Per (row,j): 2 v_and + 2 v_pk_max_f16 (vs 6 VALU f32) and half the bytes.
// Valid: z >= 0, diag bit set, AND-with-zero yields +0.0h.
template<int RT, int JS>
__global__ __launch_bounds__(256, 8) void k_mmax256h(const unsigned* __restrict__ mb,
                                                     const unsigned* __restrict__ zh,
                                                     float* __restrict__ part) {
    constexpr int JPS = NN / JS;   // 512
    constexpr int WPS = JPS / 32;  // 16
    constexpr int RPG = RT / 4;    // 4
    constexpr int NRB = NN / RT;   // 256
    int rowblk = blockIdx.x % NRB, js = blockIdx.x / NRB;
    int i0 = rowblk * RT;

    __shared__ unsigned msk[RT][WPS + 1];
    {
        int t = threadIdx.x;           // RT*WPS == 256
        msk[t / WPS][t % WPS] = mb[(size_t)(i0 + t / WPS) * 128 + js * WPS + t % WPS];
    }
    __syncthreads();

    int d = threadIdx.x & 63;
    int g = threadIdx.x >> 6;
    const uint2* zbase = (const uint2*)zh + (size_t)js * JPS * 64 + d;   // row = 64 uint2

    uint2 acc[RPG];
    #pragma unroll
    for (int r = 0; r < RPG; ++r) acc[r] = make_uint2(0u, 0u);

    #pragma unroll 1
    for (int wq = 0; wq < WPS; ++wq) {
        unsigned m[RPG];
        #pragma unroll
        for (int r = 0; r < RPG; ++r)
            m[r] = (unsigned)__builtin_amdgcn_readfirstlane((int)msk[g * RPG + r][wq]);
        const uint2* zp = zbase + (size_t)(wq * 32) * 64;
        #pragma unroll 2
        for (int j4 = 0; j4 < 32; j4 += 4) {
            uint2 z0 = zp[0 * 64];
            uint2 z1 = zp[1 * 64];
            uint2 z2 = zp[2 * 64];
            uint2 z3 = zp[3 * 64];
            #pragma unroll
            for (int r = 0; r < RPG; ++r) {
                unsigned s0 = bit_sext_s(m[r], j4 + 0);
                unsigned s1 = bit_sext_s(m[r], j4 + 1);
                unsigned s2 = bit_sext_s(m[r], j4 + 2);
                unsigned s3 = bit_sext_s(m[r], j4 + 3);
                pkmax(acc[r].x, s0 & z0.x); pkmax(acc[r].y, s0 & z0.y);
                pkmax(acc[r].x, s1 & z1.x); pkmax(acc[r].y, s1 & z1.y);
                pkmax(acc[r].x, s2 & z2.x); pkmax(acc[r].y, s2 & z2.y);
                pkmax(acc[r].x, s3 & z3.x); pkmax(acc[r].y, s3 & z3.y);
            }
            zp += 4 * 64;
        }
    }

    float4* po = (float4*)(part + (size_t)js * NN * 256);
    #pragma unroll
    for (int r = 0; r < RPG; ++r) {
        __half2 h0 = *(__half2*)&acc[r].x;
        __half2 h1 = *(__half2*)&acc[r].y;
        float2 f0 = __half22float2(h0);
        float2 f1 = __half22float2(h1);
        po[(size_t)(i0 + g * RPG + r) * 64 + d] = make_float4(f0.x, f0.y, f1.x, f1.y);
    }
}

// Masked max, D=128, f32 (unchanged round-13 structure).
template<int RT, int JS>
__global__ __launch_bounds__(256, 8) void k_mmax128(const unsigned* __restrict__ mb,
                                                    const float* __restrict__ z,
                                                    float* __restrict__ part) {
    constexpr int JPS = NN / JS;   // 512
    constexpr int WPS = JPS / 32;  // 16
    constexpr int RPG = RT / 4;    // 4
    constexpr int NRB = NN / RT;   // 256
    int rowblk = blockIdx.x % NRB, js = blockIdx.x / NRB;
    int i0 = rowblk * RT;

    __shared__ unsigned msk[RT][WPS + 1];
    {
        int t = threadIdx.x;
        msk[t / WPS][t % WPS] = mb[(size_t)(i0 + t / WPS) * 128 + js * WPS + t % WPS];
    }
    __syncthreads();

    int lane = threadIdx.x & 63;
    int g = threadIdx.x >> 6;
    unsigned jpar = lane >> 5;
    int d4 = lane & 31;
    const float4* zbase = (const float4*)z + (size_t)js * JPS * 32 + d4;

    float4 acc[RPG];
    #pragma unroll
    for (int r = 0; r < RPG; ++r) acc[r] = make_float4(0.f, 0.f, 0.f, 0.f);

    #pragma unroll 1
    for (int wq = 0; wq < WPS; ++wq) {
        unsigned m[RPG];
        #pragma unroll
        for (int r = 0; r < RPG; ++r)
            m[r] = (unsigned)__builtin_amdgcn_readfirstlane((int)msk[g * RPG + r][wq]);
        const float4* zp = zbase + (size_t)(wq * 32) * 32;
        #pragma unroll 2
        for (int j4 = 0; j4 < 32; j4 += 4) {
            float4 za = zp[(size_t)jpar * 32];
            float4 zb = zp[(size_t)(2 + jpar) * 32];
            unsigned oa = j4 + jpar, ob = j4 + 2 + jpar;
            #pragma unroll
            for (int r = 0; r < RPG; ++r) {
                unsigned sa = vbfe1(m[r], oa);
                unsigned sb = vbfe1(m[r], ob);
                max3v(acc[r], andv_v(sa, za), andv_v(sb, zb));
            }
            zp += 4 * 32;
        }
    }

    #pragma unroll
    for (int r = 0; r < RPG; ++r) {
        acc[r].x = fmaxf(acc[r].x, __shfl_xor(acc[r].x, 32, 64));
        acc[r].y = fmaxf(acc[r].y, __shfl_xor(acc[r].y, 32, 64));
        acc[r].z = fmaxf(acc[r].z, __shfl_xor(acc[r].z, 32, 64));
        acc[r].w = fmaxf(acc[r].w, __shfl_xor(acc[r].w, 32, 64));
    }
    if (!jpar) {
        float4* po = (float4*)(part + (size_t)js * NN * 128);
        #pragma unroll
        for (int r = 0; r < RPG; ++r)
            po[(size_t)(i0 + g * RPG + r) * 32 + d4] = acc[r];
    }
}

// Final 128->32 GEMM with NS-way partial merge, LDS-staged. 4 rows per block.
template<int NS>
__global__ void k_gemm_final(const float* __restrict__ X, size_t xstride,
                             const float* __restrict__ W,
                             const float* __restrict__ b1, const float* __restrict__ b2,
                             float* __restrict__ out) {
    __shared__ float xr[4][128];
    int i0 = blockIdx.x * 4;
    for (int t = threadIdx.x; t < 512; t += 128) {
        int r = t >> 7, k = t & 127;
        float v = X[(size_t)(i0 + r) * 128 + k];
        #pragma unroll
        for (int s = 1; s < NS; ++s)
            v = fmaxf(v, X[(size_t)s * xstride + (size_t)(i0 + r) * 128 + k]);
        xr[r][k] = v;
    }
    __syncthreads();
    int il = threadIdx.x >> 5, j = threadIdx.x & 31;
    float acc = 0.0f;
    #pragma unroll 8
    for (int k = 0; k < 128; ++k) acc = fmaf(xr[il][k], W[k * 32 + j], acc);
    out[(size_t)(i0 + il) * 32 + j] = acc + b1[j] + b2[j];
}

extern "C" void kernel_launch(void* const* d_in, const int* in_sizes, int n_in,
                              void* d_out, int out_size, void* d_ws, size_t ws_size,
                              hipStream_t stream) {
    const float* inputs = (const float*)d_in[1];
    const float* feat   = (const float*)d_in[2];
    const float* u      = (const float*)d_in[3];
    const int*   src    = (const int*)d_in[4];
    const int*   dst    = (const int*)d_in[5];
    const float* gc0W = (const float*)d_in[6],  *gc0b = (const float*)d_in[7];
    const float* gc1W = (const float*)d_in[8],  *gc1b = (const float*)d_in[9];
    const float* p0W  = (const float*)d_in[10], *p0b  = (const float*)d_in[11];
    const float* l0W  = (const float*)d_in[12], *l0b  = (const float*)d_in[13];
    const float* b0   = (const float*)d_in[14];
    const float* p1W  = (const float*)d_in[15], *p1b  = (const float*)d_in[16];
    const float* l1W  = (const float*)d_in[17], *l1b  = (const float*)d_in[18];
    const float* b1   = (const float*)d_in[19];
    const float* p2W  = (const float*)d_in[20], *p2b  = (const float*)d_in[21];
    const float* l2W  = (const float*)d_in[22], *l2b  = (const float*)d_in[23];
    const float* b2   = (const float*)d_in[24];
    float* out = (float*)d_out;

    const size_t MB = 1048576;
    char* w = (char*)d_ws;
    int*      cnt_src  = (int*)(w + 0);            // 16 KB
    int*      cnt_dst  = (int*)(w + 16384);        // 16 KB
    float*    on       = (float*)(w + 32768);      // 16 KB
    float*    inn      = (float*)(w + 49152);      // 16 KB
    unsigned* smax_key = (unsigned*)(w + 65536);   // pad to 128 KB
    char*     big      = w + 131072;
    float*    tmp      = (float*)(big);            // 2 MB
    float*    agg      = (float*)(big + 2 * MB);   // 2 MB (reused as zh after GCN)
    float*    hbuf     = (float*)(big + 4 * MB);   // 2 MB
    unsigned* mb       = (unsigned*)(big + 6 * MB);// 2 MB
    float*    z        = (float*)(big + 8 * MB);   // 4 MB
    float*    pm       = (float*)(big + 12 * MB);  // 32 MB (8 split partials)
    float*    hs       = (float*)(big + 44 * MB);  // 2 MB
    float*    Sbuf     = (float*)(big + 46 * MB);  // 64 MB
    unsigned* zh       = (unsigned*)(big + 2 * MB);// alias of agg (free post-GCN)
    bool use_sstore = ws_size >= 131072 + 110 * MB;

    hipMemsetAsync(w, 0, 131072, stream);
    k_count<<<EE / 256, 256, 0, stream>>>(src, dst, cnt_src, cnt_dst);
    k_norm<<<NN / 256, 256, 0, stream>>>(cnt_src, cnt_dst, on, inn);

    // --- GCN layer 0 ---
    k_gemm_scale<256, 128, 4><<<NN / 4, 128, 0, stream>>>(inputs, gc0W, on, tmp);
    hipMemsetAsync(agg, 0, (size_t)NN * 128 * 4, stream);
    k_scatter<<<EE, 128, 0, stream>>>(tmp, src, dst, agg);
    k_gcn_out<<<NN * 128 / 256, 256, 0, stream>>>(agg, inn, gc0b, hbuf, 1);

    // --- GCN layer 1 ---
    k_gemm_scale<128, 128, 4><<<NN / 4, 128, 0, stream>>>(hbuf, gc1W, on, tmp);
    hipMemsetAsync(agg, 0, (size_t)NN * 128 * 4, stream);
    k_scatter<<<EE, 128, 0, stream>>>(tmp, src, dst, agg);
    k_gcn_out<<<NN * 128 / 256, 256, 0, stream>>>(agg, inn, gc1b, hbuf, 0);

    // --- decode: S max + mask bits ---
    dim3 tg(64, 64);
    if (use_sstore) {
        k_stile_store<<<tg, 256, 0, stream>>>(hbuf, Sbuf, smax_key);
        k_bitemit<<<tg, 256, 0, stream>>>(Sbuf, u, smax_key, mb);
    } else {
        k_stile<0><<<tg, 256, 0, stream>>>(hbuf, nullptr, smax_key, nullptr);
        k_stile<1><<<tg, 256, 0, stream>>>(hbuf, u, smax_key, mb);
    }

    // --- GraphSAGE layer 0 (256 -> 128), fp16-packed masked max ---
    k_gemm_mrg<256, 256, 1, 4, 0><<<NN / 4, 256, 0, stream>>>(feat, 0, p0W, p0b, nullptr, z, 1);
    k_f2h<<<NN * 128 / 256, 256, 0, stream>>>(z, zh);
    k_mmax256h<16, 8><<<(NN / 16) * 8, 256, 0, stream>>>(mb, zh, pm);
    k_gemm_mrg<256, 128, 8, 4, 1><<<NN / 4, 128, 0, stream>>>(pm, (size_t)NN * 256, l0W, l0b, b0, hs, 0);

    // --- GraphSAGE layer 1 (128 -> 128) ---
    k_gemm_mrg<128, 128, 1, 4, 0><<<NN / 4, 128, 0, stream>>>(hs, 0, p1W, p1b, nullptr, z, 1);
    k_mmax128<16, 8><<<(NN / 16) * 8, 256, 0, stream>>>(mb, z, pm);
    k_gemm_mrg<128, 128, 8, 4, 1><<<NN / 4, 128, 0, stream>>>(pm, (size_t)NN * 128, l1W, l1b, b1, tmp, 0);

    // --- GraphSAGE layer 2 (128 -> 32) ---
    k_gemm_mrg<128, 128, 1, 4, 0><<<NN / 4, 128, 0, stream>>>(tmp, 0, p2W, p2b, nullptr, z, 1);
    k_mmax128<16, 8><<<(NN / 16) * 8, 256, 0, stream>>>(mb, z, pm);
    k_gemm_final<8><<<NN / 4, 128, 0, stream>>>(pm, (size_t)NN * 128, l2W, l2b, b2, out);
}

// Round 16
// 673.547 us; speedup vs baseline: 1.3286x; 1.0569x over previous
//
#include <hip/hip_runtime.h>
#include <hip/hip_fp16.h>
#include <cstdint>
#include <cstddef>

#define NN 4096
#define EE 131072
#define TS 64

__device__ __forceinline__ unsigned fkey(float f) {
    unsigned u = __float_as_uint(f);
    return (u & 0x80000000u) ? ~u : (u | 0x80000000u);
}
__device__ __forceinline__ float funkey(unsigned k) {
    unsigned u = (k & 0x80000000u) ? (k & 0x7fffffffu) : ~k;
    return __uint_as_float(u);
}

// ---- VALU-only asm pins (no SALU/SCC writes; proven safe rounds 14-15) ----
__device__ __forceinline__ void pkmax(unsigned& a, unsigned x) {
    asm("v_pk_max_f16 %0, %0, %1" : "+v"(a) : "v"(x));
}
// scalar-friendly sext-bit (compiler emits SALU for wave-uniform input)
__device__ __forceinline__ unsigned bit_sext_s(unsigned w, int off) {
    return (unsigned)(((int)(w << (31 - off))) >> 31);
}

__global__ void k_count(const int* __restrict__ src, const int* __restrict__ dst,
                        int* __restrict__ cs, int* __restrict__ cd) {
    int e = blockIdx.x * 256 + threadIdx.x;
    if (e < EE) {
        atomicAdd(&cs[src[e]], 1);
        atomicAdd(&cd[dst[e]], 1);
    }
}

__global__ void k_norm(const int* __restrict__ cs, const int* __restrict__ cd,
                       float* __restrict__ on, float* __restrict__ inn) {
    int i = blockIdx.x * 256 + threadIdx.x;
    if (i < NN) {
        int a = cs[i] > 1 ? cs[i] : 1;
        int b = cd[i] > 1 ? cd[i] : 1;
        on[i]  = 1.0f / sqrtf((float)a);
        inn[i] = 1.0f / sqrtf((float)b);
    }
}

// RB rows per block: W[k][j] read once per block for RB rows.
template<int K, int ND, int RB>
__global__ void k_gemm_scale(const float* __restrict__ X, const float* __restrict__ W,
                             const float* __restrict__ scale, float* __restrict__ out) {
    __shared__ float xr[RB][K];
    int i0 = blockIdx.x * RB;
    for (int t = threadIdx.x; t < RB * K; t += ND)
        xr[t / K][t % K] = X[(size_t)(i0 + t / K) * K + t % K];
    __syncthreads();
    int j = threadIdx.x;
    float acc[RB];
    #pragma unroll
    for (int r = 0; r < RB; ++r) acc[r] = 0.0f;
    #pragma unroll 4
    for (int k = 0; k < K; ++k) {
        float w = W[k * ND + j];
        #pragma unroll
        for (int r = 0; r < RB; ++r) acc[r] = fmaf(xr[r][k], w, acc[r]);
    }
    #pragma unroll
    for (int r = 0; r < RB; ++r)
        out[(size_t)(i0 + r) * ND + j] = acc[r] * scale[i0 + r];
}

// out = (max over NS split-partials of X) @ W + b1 (+b2), RB rows/block.
// L2N=1: fused relu + l2-normalize epilogue. H16=1: relu + packed-half2 output
// (even lane pairs with odd lane via shfl_xor(1); low half = even column).
template<int K, int ND, int NS, int RB, int L2N, int H16>
__global__ void k_gemm_mrg(const float* __restrict__ X, size_t xstride,
                           const float* __restrict__ W,
                           const float* __restrict__ b1, const float* __restrict__ b2,
                           float* __restrict__ out, int do_relu) {
    __shared__ float xr[RB][K];
    int i0 = blockIdx.x * RB;
    for (int t = threadIdx.x; t < RB * K; t += ND) {
        size_t off = (size_t)(i0 + t / K) * K + t % K;
        float v = X[off];
        #pragma unroll
        for (int s = 1; s < NS; ++s) v = fmaxf(v, X[(size_t)s * xstride + off]);
        xr[t / K][t % K] = v;
    }
    __syncthreads();
    int j = threadIdx.x;
    float acc[RB];
    #pragma unroll
    for (int r = 0; r < RB; ++r) acc[r] = 0.0f;
    #pragma unroll 4
    for (int k = 0; k < K; ++k) {
        float w = W[k * ND + j];
        #pragma unroll
        for (int r = 0; r < RB; ++r) acc[r] = fmaf(xr[r][k], w, acc[r]);
    }
    if constexpr (L2N) {
        float v[RB], ss[RB];
        #pragma unroll
        for (int r = 0; r < RB; ++r) {
            float t = acc[r] + b1[j];
            if (b2) t += b2[j];
            v[r] = fmaxf(t, 0.0f);
            ss[r] = v[r] * v[r];
        }
        #pragma unroll
        for (int o = 1; o < 64; o <<= 1)
            #pragma unroll
            for (int r = 0; r < RB; ++r) ss[r] += __shfl_xor(ss[r], o, 64);
        __shared__ float sred[RB][2];
        if ((threadIdx.x & 63) == 0)
            #pragma unroll
            for (int r = 0; r < RB; ++r) sred[r][threadIdx.x >> 6] = ss[r];
        __syncthreads();
        #pragma unroll
        for (int r = 0; r < RB; ++r) {
            float tot = sred[r][0] + sred[r][1];
            out[(size_t)(i0 + r) * ND + j] = v[r] / fmaxf(sqrtf(tot), 1e-12f);
        }
    } else if constexpr (H16) {
        unsigned* oh = (unsigned*)out;
        #pragma unroll
        for (int r = 0; r < RB; ++r) {
            float v = fmaxf(acc[r] + b1[j], 0.0f);
            float o2 = __shfl_xor(v, 1, 64);
            if ((j & 1) == 0) {
                __half2 h = __floats2half2_rn(v, o2);
                oh[(size_t)(i0 + r) * (ND / 2) + (j >> 1)] = *(unsigned*)&h;
            }
        }
    } else {
        #pragma unroll
        for (int r = 0; r < RB; ++r) {
            float v = acc[r] + b1[j];
            if (b2) v += b2[j];
            if (do_relu) v = fmaxf(v, 0.0f);
            out[(size_t)(i0 + r) * ND + j] = v;
        }
    }
}

__global__ void k_scatter(const float* __restrict__ t, const int* __restrict__ src,
                          const int* __restrict__ dst, float* __restrict__ agg) {
    int e = blockIdx.x;
    int j = threadIdx.x;   // 128 threads
    int s = src[e], d = dst[e];
    atomicAdd(&agg[(size_t)d * 128 + j], t[(size_t)s * 128 + j]);
}

__global__ void k_gcn_out(const float* __restrict__ agg, const float* __restrict__ inn,
                          const float* __restrict__ b, float* __restrict__ out, int do_relu) {
    int idx = blockIdx.x * 256 + threadIdx.x;
    int i = idx >> 7, j = idx & 127;
    float v = agg[idx] * inn[i] + b[j];
    if (do_relu) v = fmaxf(v, 0.0f);
    out[idx] = v;
}

// ---- S = h h^T 64x64 tile; MODE 0: max-only; MODE 1: recompute + bit-emit ----
template<int MODE>
__global__ __launch_bounds__(256, 4) void k_stile(const float* __restrict__ h,
                                                  const float* __restrict__ u,
                                                  unsigned* __restrict__ smax_key,
                                                  unsigned* __restrict__ mb) {
    int ti = blockIdx.y, tj = blockIdx.x;
    if (tj < ti) return;
    __shared__ float Ah[TS][68];
    __shared__ float Bh[TS][68];
    int tid = threadIdx.x;
    int tx = tid & 15, ty = tid >> 4;
    const float* ha = h + (size_t)ti * TS * 128;
    const float* hb = h + (size_t)tj * TS * 128;

    float acc[4][4];
    #pragma unroll
    for (int r = 0; r < 4; ++r)
        #pragma unroll
        for (int c = 0; c < 4; ++c) acc[r][c] = 0.0f;

    for (int half = 0; half < 2; ++half) {
        __syncthreads();
        #pragma unroll
        for (int t = 0; t < 4; ++t) {
            int f = tid + t * 256;
            int row = f >> 4, kk = f & 15;
            *(float4*)&Ah[row][kk * 4] = *(const float4*)(ha + (size_t)row * 128 + half * 64 + kk * 4);
            *(float4*)&Bh[row][kk * 4] = *(const float4*)(hb + (size_t)row * 128 + half * 64 + kk * 4);
        }
        __syncthreads();
        #pragma unroll 2
        for (int k4 = 0; k4 < 16; ++k4) {
            float4 a[4], b[4];
            #pragma unroll
            for (int r = 0; r < 4; ++r) a[r] = *(const float4*)&Ah[ty + 16 * r][k4 * 4];
            #pragma unroll
            for (int c = 0; c < 4; ++c) b[c] = *(const float4*)&Bh[tx + 16 * c][k4 * 4];
            #pragma unroll
            for (int r = 0; r < 4; ++r)
                #pragma unroll
                for (int c = 0; c < 4; ++c) {
                    acc[r][c] = fmaf(a[r].x, b[c].x, acc[r][c]);
                    acc[r][c] = fmaf(a[r].y, b[c].y, acc[r][c]);
                    acc[r][c] = fmaf(a[r].z, b[c].z, acc[r][c]);
                    acc[r][c] = fmaf(a[r].w, b[c].w, acc[r][c]);
                }
        }
    }

    if constexpr (MODE == 0) {
        float m = -3.4e38f;
        #pragma unroll
        for (int r = 0; r < 4; ++r)
            #pragma unroll
            for (int c = 0; c < 4; ++c) m = fmaxf(m, acc[r][c]);
        #pragma unroll
        for (int o = 1; o < 64; o <<= 1) m = fmaxf(m, __shfl_xor(m, o, 64));
        __shared__ float wm[4];
        if ((tid & 63) == 0) wm[tid >> 6] = m;
        __syncthreads();
        if (tid == 0) {
            float mm = fmaxf(fmaxf(wm[0], wm[1]), fmaxf(wm[2], wm[3]));
            atomicMax(smax_key, fkey(mm));
        }
    } else {
        float smax = funkey(*smax_key);
        float epmax = 1.0f / (1.0f + expf(-smax));
        __shared__ unsigned lm[TS][2];
        __shared__ unsigned lmT[TS][2];
        if (tid < 128) { lm[tid >> 1][tid & 1] = 0u; lmT[tid >> 1][tid & 1] = 0u; }
        __syncthreads();
        #pragma unroll
        for (int r = 0; r < 4; ++r) {
            #pragma unroll
            for (int c = 0; c < 4; ++c) {
                int li = ty + 16 * r, lj = tx + 16 * c;
                int gi = ti * TS + li, gj = tj * TS + lj;
                bool bit = false;
                if (gi < gj) {
                    float ep = 1.0f / (1.0f + expf(-acc[r][c]));
                    float P = ep / epmax;
                    float Pc = fminf(fmaxf(P, 1e-6f), 1.0f - 1e-6f);
                    float uu = u[(size_t)gi * NN + gj];
                    float ucv = fminf(fmaxf(uu, 1e-6f), 1.0f - 1e-6f);
                    bit = Pc > (1.0f - ucv);
                } else if (gi == gj) {
                    bit = true;
                }
                if (bit) {
                    atomicOr(&lm[li][lj >> 5], 1u << (lj & 31));
                    atomicOr(&lmT[lj][li >> 5], 1u << (li & 31));
                }
            }
        }
        __syncthreads();
        if (tid < 128) {
            int r = tid >> 1, wq = tid & 1;
            unsigned word = lm[r][wq];
            if (ti == tj) word |= lmT[r][wq];
            mb[(size_t)(ti * TS + r) * 128 + tj * 2 + wq] = word;
        } else if (ti != tj) {
            int r = (tid - 128) >> 1, wq = tid & 1;
            mb[(size_t)(tj * TS + r) * 128 + ti * 2 + wq] = lmT[r][wq];
        }
    }
}

// Pass 1 (S-store path): compute tile, store S to ws, fold into global max.
__global__ __launch_bounds__(256, 4) void k_stile_store(const float* __restrict__ h,
                                                        float* __restrict__ S,
                                                        unsigned* __restrict__ smax_key) {
    int ti = blockIdx.y, tj = blockIdx.x;
    if (tj < ti) return;
    __shared__ float Ah[TS][68];
    __shared__ float Bh[TS][68];
    int tid = threadIdx.x;
    int tx = tid & 15, ty = tid >> 4;
    const float* ha = h + (size_t)ti * TS * 128;
    const float* hb = h + (size_t)tj * TS * 128;

    float acc[4][4];
    #pragma unroll
    for (int r = 0; r < 4; ++r)
        #pragma unroll
        for (int c = 0; c < 4; ++c) acc[r][c] = 0.0f;

    for (int half = 0; half < 2; ++half) {
        __syncthreads();
        #pragma unroll
        for (int t = 0; t < 4; ++t) {
            int f = tid + t * 256;
            int row = f >> 4, kk = f & 15;
            *(float4*)&Ah[row][kk * 4] = *(const float4*)(ha + (size_t)row * 128 + half * 64 + kk * 4);
            *(float4*)&Bh[row][kk * 4] = *(const float4*)(hb + (size_t)row * 128 + half * 64 + kk * 4);
        }
        __syncthreads();
        #pragma unroll 2
        for (int k4 = 0; k4 < 16; ++k4) {
            float4 a[4], b[4];
            #pragma unroll
            for (int r = 0; r < 4; ++r) a[r] = *(const float4*)&Ah[ty + 16 * r][k4 * 4];
            #pragma unroll
            for (int c = 0; c < 4; ++c) b[c] = *(const float4*)&Bh[tx + 16 * c][k4 * 4];
            #pragma unroll
            for (int r = 0; r < 4; ++r)
                #pragma unroll
                for (int c = 0; c < 4; ++c) {
                    acc[r][c] = fmaf(a[r].x, b[c].x, acc[r][c]);
                    acc[r][c] = fmaf(a[r].y, b[c].y, acc[r][c]);
                    acc[r][c] = fmaf(a[r].z, b[c].z, acc[r][c]);
                    acc[r][c] = fmaf(a[r].w, b[c].w, acc[r][c]);
                }
        }
    }

    float* sp = S + (size_t)(ti * 64 + tj) * 4096;
    #pragma unroll
    for (int r = 0; r < 4; ++r)
        #pragma unroll
        for (int c = 0; c < 4; ++c)
            sp[(ty + 16 * r) * 64 + tx + 16 * c] = acc[r][c];

    float m = -3.4e38f;
    #pragma unroll
    for (int r = 0; r < 4; ++r)
        #pragma unroll
        for (int c = 0; c < 4; ++c) m = fmaxf(m, acc[r][c]);
    #pragma unroll
    for (int o = 1; o < 64; o <<= 1) m = fmaxf(m, __shfl_xor(m, o, 64));
    __shared__ float wm[4];
    if ((tid & 63) == 0) wm[tid >> 6] = m;
    __syncthreads();
    if (tid == 0)
        atomicMax(smax_key, fkey(fmaxf(fmaxf(wm[0], wm[1]), fmaxf(wm[2], wm[3]))));
}

// Pass 2 (S-store path): read stored S, emit mask bits.
__global__ __launch_bounds__(256, 4) void k_bitemit(const float* __restrict__ S,
                                                    const float* __restrict__ u,
                                                    const unsigned* __restrict__ smax_key,
                                                    unsigned* __restrict__ mb) {
    int ti = blockIdx.y, tj = blockIdx.x;
    if (tj < ti) return;
    int tid = threadIdx.x;
    int tx = tid & 15, ty = tid >> 4;
    float smax = funkey(*smax_key);
    float epmax = 1.0f / (1.0f + expf(-smax));
    __shared__ unsigned lm[TS][2];
    __shared__ unsigned lmT[TS][2];
    if (tid < 128) { lm[tid >> 1][tid & 1] = 0u; lmT[tid >> 1][tid & 1] = 0u; }
    __syncthreads();
    const float* sp = S + (size_t)(ti * 64 + tj) * 4096;
    #pragma unroll
    for (int r = 0; r < 4; ++r) {
        #pragma unroll
        for (int c = 0; c < 4; ++c) {
            int li = ty + 16 * r, lj = tx + 16 * c;
            int gi = ti * TS + li, gj = tj * TS + lj;
            bool bit = false;
            if (gi < gj) {
                float ep = 1.0f / (1.0f + expf(-sp[li * 64 + lj]));
                float P = ep / epmax;
                float Pc = fminf(fmaxf(P, 1e-6f), 1.0f - 1e-6f);
                float uu = u[(size_t)gi * NN + gj];
                float ucv = fminf(fmaxf(uu, 1e-6f), 1.0f - 1e-6f);
                bit = Pc > (1.0f - ucv);
            } else if (gi == gj) {
                bit = true;
            }
            if (bit) {
                atomicOr(&lm[li][lj >> 5], 1u << (lj & 31));
                atomicOr(&lmT[lj][li >> 5], 1u << (li & 31));
            }
        }
    }
    __syncthreads();
    if (tid < 128) {
        int r = tid >> 1, wq = tid & 1;
        unsigned word = lm[r][wq];
        if (ti == tj) word |= lmT[r][wq];
        mb[(size_t)(ti * TS + r) * 128 + tj * 2 + wq] = word;
    } else if (ti != tj) {
        int r = (tid - 128) >> 1, wq = tid & 1;
        mb[(size_t)(tj * TS + r) * 128 + ti * 2 + wq] = lmT[r][wq];
    }
}

// Masked max, D=256, fp16-packed z (row = 128 u32; lane d covers u32 [2d,2d+2)).
template<int RT, int JS>
__global__ __launch_bounds__(256, 8) void k_mmax256h(const unsigned* __restrict__ mb,
                                                     const unsigned* __restrict__ zh,
                                                     float* __restrict__ part) {
    constexpr int JPS = NN / JS;   // 512
    constexpr int WPS = JPS / 32;  // 16
    constexpr int RPG = RT / 4;    // 4
    constexpr int NRB = NN / RT;   // 256
    int rowblk = blockIdx.x % NRB, js = blockIdx.x / NRB;
    int i0 = rowblk * RT;

    __shared__ unsigned msk[RT][WPS + 1];
    {
        int t = threadIdx.x;           // RT*WPS == 256
        msk[t / WPS][t % WPS] = mb[(size_t)(i0 + t / WPS) * 128 + js * WPS + t % WPS];
    }
    __syncthreads();

    int d = threadIdx.x & 63;
    int g = threadIdx.x >> 6;
    const uint2* zbase = (const uint2*)zh + (size_t)js * JPS * 64 + d;   // row = 64 uint2

    uint2 acc[RPG];
    #pragma unroll
    for (int r = 0; r < RPG; ++r) acc[r] = make_uint2(0u, 0u);

    #pragma unroll 1
    for (int wq = 0; wq < WPS; ++wq) {
        unsigned m[RPG];
        #pragma unroll
        for (int r = 0; r < RPG; ++r)
            m[r] = (unsigned)__builtin_amdgcn_readfirstlane((int)msk[g * RPG + r][wq]);
        const uint2* zp = zbase + (size_t)(wq * 32) * 64;
        #pragma unroll 2
        for (int j4 = 0; j4 < 32; j4 += 4) {
            uint2 z0 = zp[0 * 64];
            uint2 z1 = zp[1 * 64];
            uint2 z2 = zp[2 * 64];
            uint2 z3 = zp[3 * 64];
            #pragma unroll
            for (int r = 0; r < RPG; ++r) {
                unsigned s0 = bit_sext_s(m[r], j4 + 0);
                unsigned s1 = bit_sext_s(m[r], j4 + 1);
                unsigned s2 = bit_sext_s(m[r], j4 + 2);
                unsigned s3 = bit_sext_s(m[r], j4 + 3);
                pkmax(acc[r].x, s0 & z0.x); pkmax(acc[r].y, s0 & z0.y);
                pkmax(acc[r].x, s1 & z1.x); pkmax(acc[r].y, s1 & z1.y);
                pkmax(acc[r].x, s2 & z2.x); pkmax(acc[r].y, s2 & z2.y);
                pkmax(acc[r].x, s3 & z3.x); pkmax(acc[r].y, s3 & z3.y);
            }
            zp += 4 * 64;
        }
    }

    float4* po = (float4*)(part + (size_t)js * NN * 256);
    #pragma unroll
    for (int r = 0; r < RPG; ++r) {
        __half2 h0 = *(__half2*)&acc[r].x;
        __half2 h1 = *(__half2*)&acc[r].y;
        float2 f0 = __half22float2(h0);
        float2 f1 = __half22float2(h1);
        po[(size_t)(i0 + g * RPG + r) * 64 + d] = make_float4(f0.x, f0.y, f1.x, f1.y);
    }
}

// Masked max, D=128, fp16-packed z (row = 64 u32). Wave halves: lanes 0-31
// cover row j (uint2 each = 4 halves), lanes 32-63 cover row j+1; merged by
// shfl_xor(32) + pkmax at the end. 1 v_and + 1 v_pk_max per (row,j) per half.
template<int RT, int JS>
__global__ __launch_bounds__(256, 8) void k_mmax128h(const unsigned* __restrict__ mb,
                                                     const unsigned* __restrict__ zh,
                                                     float* __restrict__ part) {
    constexpr int JPS = NN / JS;   // 512
    constexpr int WPS = JPS / 32;  // 16
    constexpr int RPG = RT / 4;    // 4
    constexpr int NRB = NN / RT;   // 256
    int rowblk = blockIdx.x % NRB, js = blockIdx.x / NRB;
    int i0 = rowblk * RT;

    __shared__ unsigned msk[RT][WPS + 1];
    {
        int t = threadIdx.x;
        msk[t / WPS][t % WPS] = mb[(size_t)(i0 + t / WPS) * 128 + js * WPS + t % WPS];
    }
    __syncthreads();

    int lane = threadIdx.x & 63;
    int g = threadIdx.x >> 6;
    unsigned jpar = lane >> 5;
    int d2 = lane & 31;                 // uint2 index within row (32 uint2 = 64 u32)
    const uint2* zbase = (const uint2*)zh + (size_t)js * JPS * 32 + d2;

    uint2 acc[RPG];
    #pragma unroll
    for (int r = 0; r < RPG; ++r) acc[r] = make_uint2(0u, 0u);

    #pragma unroll 1
    for (int wq = 0; wq < WPS; ++wq) {
        unsigned m[RPG];
        #pragma unroll
        for (int r = 0; r < RPG; ++r)
            m[r] = (unsigned)__builtin_amdgcn_readfirstlane((int)msk[g * RPG + r][wq]);
        const uint2* zp = zbase + (size_t)(wq * 32) * 32;
        #pragma unroll 2
        for (int j4 = 0; j4 < 32; j4 += 4) {
            uint2 za = zp[(size_t)jpar * 32];
            uint2 zb = zp[(size_t)(2 + jpar) * 32];
            int oa = j4 + (int)jpar, ob = j4 + 2 + (int)jpar;
            #pragma unroll
            for (int r = 0; r < RPG; ++r) {
                unsigned sa = bit_sext_s(m[r], oa);   // mask uniform; offset half-uniform
                unsigned sb = bit_sext_s(m[r], ob);
                pkmax(acc[r].x, sa & za.x); pkmax(acc[r].y, sa & za.y);
                pkmax(acc[r].x, sb & zb.x); pkmax(acc[r].y, sb & zb.y);
            }
            zp += 4 * 32;
        }
    }

    // merge the two j-halves of the wave (pkmax across shfl)
    #pragma unroll
    for (int r = 0; r < RPG; ++r) {
        unsigned ox = __shfl_xor(acc[r].x, 32, 64);
        unsigned oy = __shfl_xor(acc[r].y, 32, 64);
        pkmax(acc[r].x, ox);
        pkmax(acc[r].y, oy);
    }
    if (!jpar) {
        float4* po = (float4*)(part + (size_t)js * NN * 128);
        #pragma unroll
        for (int r = 0; r < RPG; ++r) {
            __half2 h0 = *(__half2*)&acc[r].x;
            __half2 h1 = *(__half2*)&acc[r].y;
            float2 f0 = __half22float2(h0);
            float2 f1 = __half22float2(h1);
            po[(size_t)(i0 + g * RPG + r) * 32 + d2] = make_float4(f0.x, f0.y, f1.x, f1.y);
        }
    }
}

// Final 128->32 GEMM with NS-way partial merge, LDS-staged. 4 rows per block.
template<int NS>
__global__ void k_gemm_final(const float* __restrict__ X, size_t xstride,
                             const float* __restrict__ W,
                             const float* __restrict__ b1, const float* __restrict__ b2,
                             float* __restrict__ out) {
    __shared__ float xr[4][128];
    int i0 = blockIdx.x * 4;
    for (int t = threadIdx.x; t < 512; t += 128) {
        int r = t >> 7, k = t & 127;
        float v = X[(size_t)(i0 + r) * 128 + k];
        #pragma unroll
        for (int s = 1; s < NS; ++s)
            v = fmaxf(v, X[(size_t)s * xstride + (size_t)(i0 + r) * 128 + k]);
        xr[r][k] = v;
    }
    __syncthreads();
    int il = threadIdx.x >> 5, j = threadIdx.x & 31;
    float acc = 0.0f;
    #pragma unroll 8
    for (int k = 0; k < 128; ++k) acc = fmaf(xr[il][k], W[k * 32 + j], acc);
    out[(size_t)(i0 + il) * 32 + j] = acc + b1[j] + b2[j];
}

extern "C" void kernel_launch(void* const* d_in, const int* in_sizes, int n_in,
                              void* d_out, int out_size, void* d_ws, size_t ws_size,
                              hipStream_t stream) {
    const float* inputs = (const float*)d_in[1];
    const float* feat   = (const float*)d_in[2];
    const float* u      = (const float*)d_in[3];
    const int*   src    = (const int*)d_in[4];
    const int*   dst    = (const int*)d_in[5];
    const float* gc0W = (const float*)d_in[6],  *gc0b = (const float*)d_in[7];
    const float* gc1W = (const float*)d_in[8],  *gc1b = (const float*)d_in[9];
    const float* p0W  = (const float*)d_in[10], *p0b  = (const float*)d_in[11];
    const float* l0W  = (const float*)d_in[12], *l0b  = (const float*)d_in[13];
    const float* b0   = (const float*)d_in[14];
    const float* p1W  = (const float*)d_in[15], *p1b  = (const float*)d_in[16];
    const float* l1W  = (const float*)d_in[17], *l1b  = (const float*)d_in[18];
    const float* b1   = (const float*)d_in[19];
    const float* p2W  = (const float*)d_in[20], *p2b  = (const float*)d_in[21];
    const float* l2W  = (const float*)d_in[22], *l2b  = (const float*)d_in[23];
    const float* b2   = (const float*)d_in[24];
    float* out = (float*)d_out;

    const size_t MB = 1048576;
    char* w = (char*)d_ws;
    int*      cnt_src  = (int*)(w + 0);            // 16 KB
    int*      cnt_dst  = (int*)(w + 16384);        // 16 KB
    float*    on       = (float*)(w + 32768);      // 16 KB
    float*    inn      = (float*)(w + 49152);      // 16 KB
    unsigned* smax_key = (unsigned*)(w + 65536);   // pad to 128 KB
    char*     big      = w + 131072;
    float*    tmp      = (float*)(big);            // 2 MB
    float*    agg      = (float*)(big + 2 * MB);   // 2 MB
    float*    hbuf     = (float*)(big + 4 * MB);   // 2 MB
    unsigned* mb       = (unsigned*)(big + 6 * MB);// 2 MB
    unsigned* zh       = (unsigned*)(big + 8 * MB);// 2 MB (fp16-packed z)
    float*    pm       = (float*)(big + 12 * MB);  // 32 MB (8 split partials)
    float*    hs       = (float*)(big + 44 * MB);  // 2 MB
    float*    Sbuf     = (float*)(big + 46 * MB);  // 64 MB
    bool use_sstore = ws_size >= 131072 + 110 * MB;

    hipMemsetAsync(w, 0, 131072, stream);
    k_count<<<EE / 256, 256, 0, stream>>>(src, dst, cnt_src, cnt_dst);
    k_norm<<<NN / 256, 256, 0, stream>>>(cnt_src, cnt_dst, on, inn);

    // --- GCN layer 0 ---
    k_gemm_scale<256, 128, 4><<<NN / 4, 128, 0, stream>>>(inputs, gc0W, on, tmp);
    hipMemsetAsync(agg, 0, (size_t)NN * 128 * 4, stream);
    k_scatter<<<EE, 128, 0, stream>>>(tmp, src, dst, agg);
    k_gcn_out<<<NN * 128 / 256, 256, 0, stream>>>(agg, inn, gc0b, hbuf, 1);

    // --- GCN layer 1 ---
    k_gemm_scale<128, 128, 4><<<NN / 4, 128, 0, stream>>>(hbuf, gc1W, on, tmp);
    hipMemsetAsync(agg, 0, (size_t)NN * 128 * 4, stream);
    k_scatter<<<EE, 128, 0, stream>>>(tmp, src, dst, agg);
    k_gcn_out<<<NN * 128 / 256, 256, 0, stream>>>(agg, inn, gc1b, hbuf, 0);

    // --- decode: S max + mask bits ---
    dim3 tg(64, 64);
    if (use_sstore) {
        k_stile_store<<<tg, 256, 0, stream>>>(hbuf, Sbuf, smax_key);
        k_bitemit<<<tg, 256, 0, stream>>>(Sbuf, u, smax_key, mb);
    } else {
        k_stile<0><<<tg, 256, 0, stream>>>(hbuf, nullptr, smax_key, nullptr);
        k_stile<1><<<tg, 256, 0, stream>>>(hbuf, u, smax_key, mb);
    }

    // --- GraphSAGE layer 0 (256 -> 128), fp16-packed masked max ---
    k_gemm_mrg<256, 256, 1, 4, 0, 1><<<NN / 4, 256, 0, stream>>>(feat, 0, p0W, p0b, nullptr, (float*)zh, 1);
    k_mmax256h<16, 8><<<(NN / 16) * 8, 256, 0, stream>>>(mb, zh, pm);
    k_gemm_mrg<256, 128, 8, 4, 1, 0><<<NN / 4, 128, 0, stream>>>(pm, (size_t)NN * 256, l0W, l0b, b0, hs, 0);

    // --- GraphSAGE layer 1 (128 -> 128), fp16 ---
    k_gemm_mrg<128, 128, 1, 4, 0, 1><<<NN / 4, 128, 0, stream>>>(hs, 0, p1W, p1b, nullptr, (float*)zh, 1);
    k_mmax128h<16, 8><<<(NN / 16) * 8, 256, 0, stream>>>(mb, zh, pm);
    k_gemm_mrg<128, 128, 8, 4, 1, 0><<<NN / 4, 128, 0, stream>>>(pm, (size_t)NN * 128, l1W, l1b, b1, tmp, 0);

    // --- GraphSAGE layer 2 (128 -> 32), fp16 ---
    k_gemm_mrg<128, 128, 1, 4, 0, 1><<<NN / 4, 128, 0, stream>>>(tmp, 0, p2W, p2b, nullptr, (float*)zh, 1);
    k_mmax128h<16, 8><<<(NN / 16) * 8, 256, 0, stream>>>(mb, zh, pm);
    k_gemm_final<8><<<NN / 4, 128, 0, stream>>>(pm, (size_t)NN * 128, l2W, l2b, b2, out);
}